// Round 9
// baseline (486.698 us; speedup 1.0000x reference)
//
#include <hip/hip_runtime.h>
#include <hip/hip_bf16.h>
#include <cstdint>
#include <cstddef>

// Problem constants (fixed by setup_inputs)
#define LSEQ   4096
#define DHD    64
#define NHASH  4
#define CDIM   512
#define NBH    32        // B*HEADS
#define MROWS  16384     // B*LSEQ
#define NCHUNK 256       // NHASH*LSEQ/64

typedef __attribute__((ext_vector_type(8))) short short8;
typedef __attribute__((ext_vector_type(4))) float f32x4;
typedef __attribute__((ext_vector_type(2))) float f32x2;

__device__ inline uint32_t f2bf(float f) {
  uint32_t u = __float_as_uint(f);
  return (u + 0x7FFFu + ((u >> 16) & 1u)) >> 16;
}
__device__ inline float bf2f(uint32_t h) { return __uint_as_float(h << 16); }
__device__ inline void split2(float f, uint32_t& hi, uint32_t& lo) {
  hi = f2bf(f);
  lo = f2bf(f - bf2f(hi));
}
// HW packed f32->bf16 (RNE, same bits as f2bf for normal values):
// low16 = bf16(a), high16 = bf16(b)
__device__ inline uint32_t cvtpk_bf16(float a, float b) {
  uint32_t r;
  asm("v_cvt_pk_bf16_f32 %0, %1, %2" : "=v"(r) : "v"(a), "v"(b));
  return r;
}
__device__ inline short8 ldsK(const uint16_t* p) {   // two b64 reads -> short8
  union { uint2 u[2]; short8 s; } t;
  t.u[0] = *reinterpret_cast<const uint2*>(p);
  t.u[1] = *reinterpret_cast<const uint2*>(p + 4);
  return t.s;
}

// ---------------------------------------------------------------------------
// K0: fused prep.  blocks [0,8192): X->2 bf16 planes; [8192,9216): Wo split+
// transpose; [9216,9472): Wv split+transpose.  UNCHANGED from r8.
// ---------------------------------------------------------------------------
__global__ __launch_bounds__(256) void prep_kernel(
    const float* __restrict__ X, const float* __restrict__ Wv,
    const float* __restrict__ Wo,
    uint16_t* __restrict__ X0, uint16_t* __restrict__ X1,
    uint16_t* __restrict__ wvT0, uint16_t* __restrict__ wvT1,
    uint16_t* __restrict__ woT_hi, uint16_t* __restrict__ woT_lo)
{
  __shared__ float Ts[32][33];
  const int bid = blockIdx.x, tid = threadIdx.x;
  if (bid < 8192) {
    size_t i = ((size_t)bid * 256 + tid) * 4;
    float4 v = *reinterpret_cast<const float4*>(X + i);
    uint32_t h01 = cvtpk_bf16(v.x, v.y);
    uint32_t h23 = cvtpk_bf16(v.z, v.w);
    float r0 = v.x - __uint_as_float(h01 << 16);
    float r1 = v.y - __uint_as_float(h01 & 0xffff0000u);
    float r2 = v.z - __uint_as_float(h23 << 16);
    float r3 = v.w - __uint_as_float(h23 & 0xffff0000u);
    uint2 hw = {h01, h23};
    uint2 lw = {cvtpk_bf16(r0, r1), cvtpk_bf16(r2, r3)};
    *reinterpret_cast<uint2*>(X0 + i) = hw;
    *reinterpret_cast<uint2*>(X1 + i) = lw;
  } else if (bid < 9216) {
    int idx = (bid - 8192) * 256 + tid;   // k*512 + n
    int k = idx >> 9, n = idx & 511;
    uint32_t hi, lo;
    split2(Wo[idx], hi, lo);
    woT_hi[n * 512 + k] = (uint16_t)hi;
    woT_lo[n * 512 + k] = (uint16_t)lo;
  } else {
    int wb = bid - 9216;                  // 0..255
    const int k0 = (wb >> 4) * 32, n0 = (wb & 15) * 32;
#pragma unroll
    for (int i = 0; i < 4; i++) {
      int flat = i * 256 + tid;
      int r = flat >> 5, c = flat & 31;
      Ts[r][c] = Wv[(size_t)(k0 + r) * 512 + n0 + c];
    }
    __syncthreads();
#pragma unroll
    for (int i = 0; i < 4; i++) {
      int flat = i * 256 + tid;
      int nr = flat >> 5, kc = flat & 31;
      uint32_t h, l;
      split2(Ts[kc][nr], h, l);
      size_t idx = (size_t)(n0 + nr) * 512 + k0 + kc;
      wvT0[idx] = (uint16_t)h;
      wvT1[idx] = (uint16_t)l;
    }
  }
}

// ---------------------------------------------------------------------------
// K1a: qk projection GEMM — FROZEN MATH, v4 "broadcast-B" schedule.
// Per output (t,d): identical k-ascending f32x2 `acc += {a,a}*{b,b'}`
// fmuladd chain (bitwise-proven r6/r8); a,b exact staged copies.
// Layout: lane = m-row (64 m/wave); each wave owns a uniform 32-col n-slice.
//   A: ds_read_b32, stride-33 pad -> 1 word/lane, conflict-free.
//   B: 8 uniform-address ds_read_b128 -> HW broadcast (~free).
// Tile 64m x 128n, block 256 (4 waves), grid (256,4).  LDS 26 KB.
// invn: cross-wave pair-sum via LDS (continuous; attn-only consumer).
// ---------------------------------------------------------------------------
__global__ __launch_bounds__(256) void gemm_qk_kernel(
    const float* __restrict__ X, const float* __restrict__ Wqk,
    float* __restrict__ qk, uint16_t* __restrict__ qkhi,
    uint16_t* __restrict__ qklo, float* __restrict__ invn_g)
{
  __shared__ float As[64 * 33];     // [m][k], stride 33
  __shared__ float Bs[32 * 132];    // [k][n], stride 132 (16B-aligned rows)
  __shared__ float part[4][64];
  const int tid = threadIdx.x;
  const int m0 = blockIdx.x * 64;
  const int n0 = blockIdx.y * 128;
  const int lane = tid & 63;
  const int w = __builtin_amdgcn_readfirstlane(tid >> 6);   // wave id 0..3
  const int wn = w * 32;            // wave's local n-offset in Bs

  f32x2 acc2[16];
#pragma unroll
  for (int j = 0; j < 16; j++) acc2[j] = {0.f, 0.f};

  const int arow = tid >> 2;            // 0..63
  const int akc  = (tid & 3) * 8;       // k chunk of 8
  const int bk   = tid >> 3;            // 0..31
  const int bnc  = (tid & 7) * 16;      // n chunk of 16

  for (int kb = 0; kb < CDIM; kb += 32) {
    __syncthreads();   // previous tile's reads complete
    // stage A (exact copies): X[m0+arow][kb+akc..+7] -> As[arow][akc..+7]
    {
      float4 x0 = *reinterpret_cast<const float4*>(&X[(size_t)(m0 + arow) * CDIM + kb + akc]);
      float4 x1 = *reinterpret_cast<const float4*>(&X[(size_t)(m0 + arow) * CDIM + kb + akc + 4]);
      float* dst = &As[arow * 33 + akc];
      dst[0] = x0.x; dst[1] = x0.y; dst[2] = x0.z; dst[3] = x0.w;
      dst[4] = x1.x; dst[5] = x1.y; dst[6] = x1.z; dst[7] = x1.w;
    }
    // stage B (exact copies): Wqk[kb+bk][n0+bnc..+15] -> Bs[bk][bnc..+15]
    {
      const float* srcb = &Wqk[(size_t)(kb + bk) * CDIM + n0 + bnc];
      float* dstb = &Bs[bk * 132 + bnc];
#pragma unroll
      for (int q = 0; q < 4; q++)
        *reinterpret_cast<float4*>(dstb + q * 4) =
            *reinterpret_cast<const float4*>(srcb + q * 4);
    }
    __syncthreads();
    // compute: per k, a = As[lane][k] (1 b32/lane), b = 8 uniform b128
#pragma unroll 8
    for (int k = 0; k < 32; k++) {
      float a = As[lane * 33 + k];
      const float4* bq = reinterpret_cast<const float4*>(&Bs[k * 132 + wn]);
      float4 b0 = bq[0], b1 = bq[1], b2 = bq[2], b3 = bq[3];
      float4 b4 = bq[4], b5 = bq[5], b6 = bq[6], b7 = bq[7];
      f32x2 av = {a, a};
      acc2[0]  += av * f32x2{b0.x, b0.y};
      acc2[1]  += av * f32x2{b0.z, b0.w};
      acc2[2]  += av * f32x2{b1.x, b1.y};
      acc2[3]  += av * f32x2{b1.z, b1.w};
      acc2[4]  += av * f32x2{b2.x, b2.y};
      acc2[5]  += av * f32x2{b2.z, b2.w};
      acc2[6]  += av * f32x2{b3.x, b3.y};
      acc2[7]  += av * f32x2{b3.z, b3.w};
      acc2[8]  += av * f32x2{b4.x, b4.y};
      acc2[9]  += av * f32x2{b4.z, b4.w};
      acc2[10] += av * f32x2{b5.x, b5.y};
      acc2[11] += av * f32x2{b5.z, b5.w};
      acc2[12] += av * f32x2{b6.x, b6.y};
      acc2[13] += av * f32x2{b6.z, b6.w};
      acc2[14] += av * f32x2{b7.x, b7.y};
      acc2[15] += av * f32x2{b7.z, b7.w};
    }
  }

  // epilogue: lane's row t = m0+lane, wave's 32 d-columns
  const int nw = n0 + wn;             // global n in 0..511
  const int head = nw >> 6;           // 0..7
  const int d0 = nw & 63;             // 0 or 32
  const int m = m0 + lane;
  const int b = m >> 12, t = m & 4095;
  const size_t base = ((size_t)(b * 8 + head) * LSEQ + t) * DHD + d0;

  float ss = 0.f;
#pragma unroll
  for (int j = 0; j < 16; j++) {
    float x = acc2[j][0], y = acc2[j][1];
    *reinterpret_cast<float2*>(&qk[base + 2 * j]) = {x, y};
    uint32_t h = cvtpk_bf16(x, y);
    float rx = x - __uint_as_float(h << 16);
    float ry = y - __uint_as_float(h & 0xffff0000u);
    reinterpret_cast<uint32_t*>(qkhi + base)[j] = h;
    reinterpret_cast<uint32_t*>(qklo + base)[j] = cvtpk_bf16(rx, ry);
    ss += x * x + y * y;
  }
  part[w][lane] = ss;
  __syncthreads();
  if ((w & 1) == 0) {
    float tot = part[w][lane] + part[w + 1][lane];
    invn_g[(size_t)(b * 8 + head) * LSEQ + t] = 1.0f / fmaxf(sqrtf(tot), 1e-12f);
  }
}

// ---------------------------------------------------------------------------
// K1b: v projection via bf16-split MFMA (3-term).  UNCHANGED from r8.
// ---------------------------------------------------------------------------
__global__ __launch_bounds__(512) void gemm_v_mfma_kernel(
    const uint16_t* __restrict__ X0g, const uint16_t* __restrict__ X1g,
    const uint16_t* __restrict__ Wv0, const uint16_t* __restrict__ Wv1,
    uint16_t* __restrict__ vhi)
{
  __shared__ __align__(16) uint16_t Xs[2 * 128 * 40];
  __shared__ __align__(16) uint16_t Ws[2 * 128 * 40];
  const int tid = threadIdx.x;
  const int m0 = blockIdx.x * 128;
  const int n0 = blockIdx.y * 128;
  const int lane = tid & 63, w = tid >> 6;
  const int l16 = lane & 15, lg = lane >> 4;

  f32x4 acc[8];
#pragma unroll
  for (int nt = 0; nt < 8; nt++) acc[nt] = {0.f, 0.f, 0.f, 0.f};

  const int srow = tid >> 3;
  const int sch = (tid & 7) * 4;

  for (int kb = 0; kb < CDIM; kb += 32) {
#pragma unroll
    for (int i = 0; i < 4; i++) {
      int p = i >> 1;
      int row = (i & 1) * 64 + srow;
      const uint16_t* xg = (p == 0) ? X0g : X1g;
      const uint16_t* wg = (p == 0) ? Wv0 : Wv1;
      *reinterpret_cast<uint2*>(Xs + p * 5120 + row * 40 + sch) =
          *reinterpret_cast<const uint2*>(xg + (size_t)(m0 + row) * 512 + kb + sch);
      *reinterpret_cast<uint2*>(Ws + p * 5120 + row * 40 + sch) =
          *reinterpret_cast<const uint2*>(wg + (size_t)(n0 + row) * 512 + kb + sch);
    }
    __syncthreads();

    const int abase = (w * 16 + l16) * 40 + lg * 8;
    short8 a0 = *reinterpret_cast<const short8*>(Xs + abase);
    short8 a1 = *reinterpret_cast<const short8*>(Xs + 5120 + abase);
#pragma unroll
    for (int nt = 0; nt < 8; nt++) {
      int bbase = (nt * 16 + l16) * 40 + lg * 8;
      short8 b0 = *reinterpret_cast<const short8*>(Ws + bbase);
      short8 b1 = *reinterpret_cast<const short8*>(Ws + 5120 + bbase);
      acc[nt] = __builtin_amdgcn_mfma_f32_16x16x32_bf16(a0, b0, acc[nt], 0, 0, 0);
      acc[nt] = __builtin_amdgcn_mfma_f32_16x16x32_bf16(a1, b0, acc[nt], 0, 0, 0);
      acc[nt] = __builtin_amdgcn_mfma_f32_16x16x32_bf16(a0, b1, acc[nt], 0, 0, 0);
    }
    __syncthreads();
  }

#pragma unroll
  for (int rr = 0; rr < 4; rr++) {
    int mg = m0 + w * 16 + lg * 4 + rr;
    int b = mg >> 12, t = mg & 4095;
#pragma unroll
    for (int nt = 0; nt < 8; nt++) {
      int head = (n0 >> 6) + (nt >> 2);
      size_t base = ((size_t)(b * 8 + head) * LSEQ + t) * DHD + (nt & 3) * 16 + l16;
      vhi[base] = (uint16_t)cvtpk_bf16(acc[nt][rr], acc[nt][rr]);
    }
  }
}

// ---------------------------------------------------------------------------
// K2: LSH hashing.  UNCHANGED (bucket determinism; reads frozen f32 qk).
// ---------------------------------------------------------------------------
__global__ __launch_bounds__(256) void hash_kernel(
    const float* __restrict__ qk, const float* __restrict__ rot,
    int* __restrict__ buckets)
{
  __shared__ float rotT[128][68];   // [h*32+i][f]
  const int tid = threadIdx.x;
  for (int idx = tid; idx < 64 * 128; idx += 256) {
    int f = idx >> 7, hi = idx & 127;
    rotT[hi][f] = rot[idx];
  }
  __syncthreads();
  const int bh = blockIdx.y;
  const int t = blockIdx.x * 256 + tid;
  float4 row4[16];
  const float* src = &qk[((size_t)bh * LSEQ + t) * DHD];
#pragma unroll
  for (int i = 0; i < 16; i++) row4[i] = reinterpret_cast<const float4*>(src)[i];

  int* bout = &buckets[(size_t)bh * NHASH * LSEQ];
  for (int h = 0; h < NHASH; h++) {
    float rc[32];
    float best = -3.0e38f;
    int bidx = 0;
#pragma unroll 4
    for (int i = 0; i < 32; i++) {
      const float* rr = &rotT[h * 32 + i][0];
      float a = 0.f;
#pragma unroll
      for (int f4 = 0; f4 < 16; f4++) {
        float4 rv = reinterpret_cast<const float4*>(rr)[f4];
        a += row4[f4].x * rv.x + row4[f4].y * rv.y + row4[f4].z * rv.z + row4[f4].w * rv.w;
      }
      rc[i] = a;
      if (a > best) { best = a; bidx = i; }
    }
#pragma unroll
    for (int i = 0; i < 32; i++) {
      float nv = -rc[i];
      if (nv > best) { best = nv; bidx = 32 + i; }
    }
    bout[h * LSEQ + t] = bidx;
  }
}

// ---------------------------------------------------------------------------
// K3: stable counting sort per (bh, h).  UNCHANGED.
// ---------------------------------------------------------------------------
__global__ __launch_bounds__(256) void sort_kernel(
    const int* __restrict__ buckets, int* __restrict__ st)
{
  __shared__ int hist[64][64];
  const int h = blockIdx.x, bh = blockIdx.y;
  const int tid = threadIdx.x;
  const int* bk = &buckets[((size_t)bh * NHASH + h) * LSEQ];

  for (int i = tid; i < 64 * 64; i += 256) (&hist[0][0])[i] = 0;
  __syncthreads();
  for (int t = tid; t < LSEQ; t += 256) {
    int b = bk[t];
    atomicAdd(&hist[t >> 6][b], 1);
  }
  __syncthreads();
  if (tid < 64) {
    int tot = 0;
    for (int s = 0; s < 64; s++) tot += hist[s][tid];
    int vsc = tot;
    for (int off = 1; off < 64; off <<= 1) {
      int nv = __shfl_up(vsc, off, 64);
      if (tid >= off) vsc += nv;
    }
    int run = h * LSEQ + (vsc - tot);
    for (int s = 0; s < 64; s++) {
      int tmp = hist[s][tid];
      hist[s][tid] = run;
      run += tmp;
    }
  }
  __syncthreads();
  const int wave = tid >> 6, lane = tid & 63;
  for (int si = 0; si < 16; si++) {
    int seg = wave * 16 + si;
    int pos = seg * 64 + lane;
    int b = bk[pos];
    int rank = 0;
    for (int k = 0; k < 64; k++) {
      int bb = __shfl(b, k, 64);
      rank += (bb == b && k < lane) ? 1 : 0;
    }
    int dest = hist[seg][b] + rank;
    st[(size_t)bh * (NHASH * LSEQ) + dest] = pos;
  }
}

// ---------------------------------------------------------------------------
// K4: chunked attention.  UNCHANGED from r8 (XCD swizzle + cvt_pk).
// ---------------------------------------------------------------------------
__global__ __launch_bounds__(256) void attn_kernel(
    const uint16_t* __restrict__ qkhi, const uint16_t* __restrict__ qklo,
    const uint16_t* __restrict__ vhi, const float* __restrict__ invn_g,
    const int* __restrict__ st, uint16_t* __restrict__ o,
    float* __restrict__ lse_out)
{
  __shared__ __align__(16) uint8_t smem[53248];
  uint16_t* Khi  = (uint16_t*)smem;                  // [128][68] = 17408 B
  uint16_t* Klo  = Khi + 128 * 68;                   // +17408 B
  uint16_t* Vthi = (uint16_t*)(smem + 34816);        // [64][128] = 16384 B
  float*    invn = (float*)(smem + 52224);           // 128 f
  int*      kpos = (int*)(smem + 52736);             // 128 i
  uint32_t* P32  = (uint32_t*)smem;                  // [64][132] u32, alias K

  // XCD-aware swizzle: lin -> (xcd, idx); each XCD gets 4 bh x 256 chunks
  const int lin = blockIdx.y * 256 + blockIdx.x;
  const int xcd = lin & 7, sidx = lin >> 3;
  const int bh = (xcd << 2) | (sidx >> 8);
  const int cchunk = sidx & 255;

  const int tid = threadIdx.x;
  const int prev = (cchunk + NCHUNK - 1) & (NCHUNK - 1);
  const int* stb = &st[(size_t)bh * (NHASH * LSEQ)];
  const int h = cchunk >> 6;

  if (tid < 128) {
    int kp = (tid < 64) ? stb[prev * 64 + tid] : stb[cchunk * 64 + (tid - 64)];
    kpos[tid] = kp;
    invn[tid] = invn_g[(size_t)bh * LSEQ + kp];
  }
  __syncthreads();

  // ---- stage K planes (pure copies) ----
  {
    const int d4 = tid & 15, rbase = tid >> 4;
    const uint16_t* qhb = qkhi + (size_t)bh * LSEQ * DHD;
    const uint16_t* qlb = qklo + (size_t)bh * LSEQ * DHD;
#pragma unroll
    for (int it = 0; it < 8; it++) {
      int row = rbase + it * 16;
      size_t src = (size_t)kpos[row] * DHD + d4 * 4;
      *reinterpret_cast<uint2*>(Khi + row * 68 + d4 * 4) =
          *reinterpret_cast<const uint2*>(qhb + src);
      *reinterpret_cast<uint2*>(Klo + row * 68 + d4 * 4) =
          *reinterpret_cast<const uint2*>(qlb + src);
    }
  }
  // ---- stage V transposed (u16 4x4 transpose), swizzled ----
  {
    const int d4 = tid & 15, jg0 = tid >> 4;
    const uint16_t* vb = vhi + (size_t)bh * LSEQ * DHD;
#pragma unroll
    for (int half = 0; half < 2; half++) {
      int jg = jg0 + half * 16;   // 0..31, j = 4*jg..4*jg+3
      uint2 vr[4];
#pragma unroll
      for (int s = 0; s < 4; s++)
        vr[s] = *reinterpret_cast<const uint2*>(vb + (size_t)kpos[jg * 4 + s] * DHD + d4 * 4);
#pragma unroll
      for (int i = 0; i < 4; i++) {
        int d = d4 * 4 + i;
        uint32_t e0 = (((i & 2) ? vr[0].y : vr[0].x) >> ((i & 1) * 16)) & 0xffffu;
        uint32_t e1 = (((i & 2) ? vr[1].y : vr[1].x) >> ((i & 1) * 16)) & 0xffffu;
        uint32_t e2 = (((i & 2) ? vr[2].y : vr[2].x) >> ((i & 1) * 16)) & 0xffffu;
        uint32_t e3 = (((i & 2) ? vr[3].y : vr[3].x) >> ((i & 1) * 16)) & 0xffffu;
        uint2 outw = {e0 | (e1 << 16), e2 | (e3 << 16)};
        int cpr = (jg >> 1) ^ (d & 15);
        *reinterpret_cast<uint2*>(Vthi + d * 128 + cpr * 8 + (jg & 1) * 4) = outw;
      }
    }
  }
  __syncthreads();

  const int lane = tid & 63, w = tid >> 6;
  const int l16 = lane & 15, lg = lane >> 4;

  // ---- QK^T (bf16x3), wave w -> q-rows 16w..16w+15 ----
  f32x4 acc[8];
#pragma unroll
  for (int nt = 0; nt < 8; nt++) acc[nt] = {0.f, 0.f, 0.f, 0.f};

#pragma unroll
  for (int ks = 0; ks < 2; ks++) {
    int aoff = (64 + w * 16 + l16) * 68 + ks * 32 + lg * 8;
    short8 a_hi = ldsK(Khi + aoff);
    short8 a_lo = ldsK(Klo + aoff);
#pragma unroll
    for (int nt = 0; nt < 8; nt++) {
      int boff = (nt * 16 + l16) * 68 + ks * 32 + lg * 8;
      short8 b_hi = ldsK(Khi + boff);
      short8 b_lo = ldsK(Klo + boff);
      acc[nt] = __builtin_amdgcn_mfma_f32_16x16x32_bf16(a_hi, b_hi, acc[nt], 0, 0, 0);
      acc[nt] = __builtin_amdgcn_mfma_f32_16x16x32_bf16(a_lo, b_hi, acc[nt], 0, 0, 0);
      acc[nt] = __builtin_amdgcn_mfma_f32_16x16x32_bf16(a_hi, b_lo, acc[nt], 0, 0, 0);
    }
  }

  // ---- register softmax on the D-layout ----
  float invc[8]; int kpc[8];
#pragma unroll
  for (int nt = 0; nt < 8; nt++) {
    invc[nt] = invn[nt * 16 + l16] * 0.125f;
    kpc[nt] = kpos[nt * 16 + l16];
  }
  float pll[4];
#pragma unroll
  for (int r = 0; r < 4; r++) {
    int q = w * 16 + lg * 4 + r;
    int qp = kpos[64 + q];
    float mm = -3.0e38f;
#pragma unroll
    for (int nt = 0; nt < 8; nt++) {
      float s = acc[nt][r] * invc[nt];
      if (qp == kpc[nt]) s = -5e4f;
      acc[nt][r] = s;
      mm = fmaxf(mm, s);
    }
    mm = fmaxf(mm, __shfl_xor(mm, 1, 64));
    mm = fmaxf(mm, __shfl_xor(mm, 2, 64));
    mm = fmaxf(mm, __shfl_xor(mm, 4, 64));
    mm = fmaxf(mm, __shfl_xor(mm, 8, 64));
    float ll = 0.f;
#pragma unroll
    for (int nt = 0; nt < 8; nt++) {
      float p = __expf(acc[nt][r] - mm);
      acc[nt][r] = p;
      ll += p;
    }
    ll += __shfl_xor(ll, 1, 64);
    ll += __shfl_xor(ll, 2, 64);
    ll += __shfl_xor(ll, 4, 64);
    ll += __shfl_xor(ll, 8, 64);
    if (l16 == 0)
      lse_out[(size_t)bh * (NHASH * LSEQ) + h * LSEQ + qp] = mm + __logf(ll);
    pll[r] = 1.0f / ll;
  }
  __syncthreads();   // all K-plane reads done; safe to alias P32

  // ---- write P (packed hi|lo u32, via cvt_pk) ----
#pragma unroll
  for (int r = 0; r < 4; r++) {
    int q = w * 16 + lg * 4 + r;
#pragma unroll
    for (int nt = 0; nt < 8; nt++) {
      float p = acc[nt][r];
      uint32_t t1 = cvtpk_bf16(p, p);
      float res = p - __uint_as_float(t1 << 16);
      P32[q * 132 + nt * 16 + l16] = cvtpk_bf16(p, res);   // low=phi, high=plo
    }
  }
  // no barrier: wave reads back only its own 16 P rows

  // ---- PV: O = P.Vhi (2-term) ----
  f32x4 oacc[4];
#pragma unroll
  for (int nt = 0; nt < 4; nt++) oacc[nt] = {0.f, 0.f, 0.f, 0.f};

#pragma unroll
  for (int ks = 0; ks < 4; ks++) {
    const uint32_t* pr = P32 + (w * 16 + l16) * 132 + ks * 32 + lg * 8;
    uint4 ua = *reinterpret_cast<const uint4*>(pr);
    uint4 ub = *reinterpret_cast<const uint4*>(pr + 4);
    uint32_t u[8] = {ua.x, ua.y, ua.z, ua.w, ub.x, ub.y, ub.z, ub.w};
    union { uint32_t w4[4]; short8 s8; } ph, pl;
#pragma unroll
    for (int k2 = 0; k2 < 4; k2++) {
      ph.w4[k2] = (u[2 * k2] & 0xffffu) | (u[2 * k2 + 1] << 16);
      pl.w4[k2] = (u[2 * k2] >> 16) | (u[2 * k2 + 1] & 0xffff0000u);
    }
    const int cc = ks * 4 + lg;
#pragma unroll
    for (int nt = 0; nt < 4; nt++) {
      int voff = (nt * 16 + l16) * 128 + ((cc ^ l16) & 15) * 8;
      short8 v_hi = *reinterpret_cast<const short8*>(Vthi + voff);
      oacc[nt] = __builtin_amdgcn_mfma_f32_16x16x32_bf16(ph.s8, v_hi, oacc[nt], 0, 0, 0);
      oacc[nt] = __builtin_amdgcn_mfma_f32_16x16x32_bf16(pl.s8, v_hi, oacc[nt], 0, 0, 0);
    }
  }

  // ---- normalize + write O (bf16, unsorted) ----
  {
    uint16_t* ob = o + ((size_t)bh * (NHASH * LSEQ) + (size_t)h * LSEQ) * DHD;
#pragma unroll
    for (int r = 0; r < 4; r++) {
      int q = w * 16 + lg * 4 + r;
      int qp = kpos[64 + q];
      float s = pll[r];
#pragma unroll
      for (int nt = 0; nt < 4; nt++) {
        float v = oacc[nt][r] * s;
        ob[(size_t)qp * DHD + nt * 16 + l16] = (uint16_t)cvtpk_bf16(v, v);
      }
    }
  }
}

// ---------------------------------------------------------------------------
// K5: combine hash rounds -> comb bf16 hi/lo planes (cvt_pk).  UNCHANGED.
// ---------------------------------------------------------------------------
__global__ __launch_bounds__(256) void combine_kernel(
    const uint16_t* __restrict__ o, const float* __restrict__ lse,
    uint16_t* __restrict__ comb_hi, uint16_t* __restrict__ comb_lo)
{
  int gid = blockIdx.x * 4 + (threadIdx.x >> 6);
  int lane = threadIdx.x & 63;
  int bh = gid >> 12;
  int pos = gid & 4095;
  const float* lb = &lse[(size_t)bh * (NHASH * LSEQ) + pos];
  float l0 = lb[0], l1 = lb[LSEQ], l2 = lb[2 * LSEQ], l3 = lb[3 * LSEQ];
  float m = fmaxf(fmaxf(l0, l1), fmaxf(l2, l3));
  float w0 = __expf(l0 - m), w1 = __expf(l1 - m), w2 = __expf(l2 - m), w3 = __expf(l3 - m);
  float inv = 1.0f / (w0 + w1 + w2 + w3);
  const uint16_t* ob = &o[((size_t)bh * (NHASH * LSEQ) + pos) * DHD];
  float val = (w0 * bf2f(ob[lane]) + w1 * bf2f(ob[(size_t)LSEQ * DHD + lane]) +
               w2 * bf2f(ob[(size_t)2 * LSEQ * DHD + lane]) +
               w3 * bf2f(ob[(size_t)3 * LSEQ * DHD + lane])) * inv;
  int b = bh >> 3, head = bh & 7;
  size_t idx = ((size_t)(b * LSEQ + pos)) * CDIM + head * DHD + lane;
  uint32_t hw = cvtpk_bf16(val, val);
  float res = val - __uint_as_float(hw << 16);
  comb_hi[idx] = (uint16_t)hw;
  comb_lo[idx] = (uint16_t)cvtpk_bf16(res, res);
}

// ---------------------------------------------------------------------------
// K6: output GEMM, bf16x3 MFMA.  UNCHANGED.
// ---------------------------------------------------------------------------
__global__ __launch_bounds__(256) void gemm_out_kernel(
    const uint16_t* __restrict__ Ahi_g, const uint16_t* __restrict__ Alo_g,
    const uint16_t* __restrict__ Bhi_g, const uint16_t* __restrict__ Blo_g,
    const float* __restrict__ bias, float* __restrict__ out)
{
  __shared__ __align__(16) uint16_t Ah[128 * 40];
  __shared__ __align__(16) uint16_t Al[128 * 40];
  __shared__ __align__(16) uint16_t Bh[128 * 40];
  __shared__ __align__(16) uint16_t Bl[128 * 40];
  const int tid = threadIdx.x;
  const int m0 = blockIdx.x * 128, n0 = blockIdx.y * 128;
  const int lane = tid & 63, w = tid >> 6;
  const int l16 = lane & 15, lg = lane >> 4;
  const int mq = w >> 1, nq = w & 1;
  f32x4 acc[4][4];
#pragma unroll
  for (int i = 0; i < 4; i++)
#pragma unroll
    for (int j = 0; j < 4; j++) acc[i][j] = {0.f, 0.f, 0.f, 0.f};

  const int srow = tid >> 1, sh = tid & 1;
  for (int kb = 0; kb < CDIM; kb += 32) {
    {
      const uint4* sa_h = (const uint4*)(Ahi_g + (size_t)(m0 + srow) * CDIM + kb + sh * 16);
      const uint4* sa_l = (const uint4*)(Alo_g + (size_t)(m0 + srow) * CDIM + kb + sh * 16);
      const uint4* sb_h = (const uint4*)(Bhi_g + (size_t)(n0 + srow) * CDIM + kb + sh * 16);
      const uint4* sb_l = (const uint4*)(Blo_g + (size_t)(n0 + srow) * CDIM + kb + sh * 16);
      uint4* da_h = (uint4*)(Ah + srow * 40 + sh * 16);
      uint4* da_l = (uint4*)(Al + srow * 40 + sh * 16);
      uint4* db_h = (uint4*)(Bh + srow * 40 + sh * 16);
      uint4* db_l = (uint4*)(Bl + srow * 40 + sh * 16);
      da_h[0] = sa_h[0]; da_h[1] = sa_h[1];
      da_l[0] = sa_l[0]; da_l[1] = sa_l[1];
      db_h[0] = sb_h[0]; db_h[1] = sb_h[1];
      db_l[0] = sb_l[0]; db_l[1] = sb_l[1];
    }
    __syncthreads();
    short8 fa_h[4], fa_l[4], fb_h[4], fb_l[4];
#pragma unroll
    for (int mt = 0; mt < 4; mt++) {
      int ao = (mq * 64 + mt * 16 + l16) * 40 + lg * 8;
      fa_h[mt] = *reinterpret_cast<const short8*>(Ah + ao);
      fa_l[mt] = *reinterpret_cast<const short8*>(Al + ao);
    }
#pragma unroll
    for (int nt = 0; nt < 4; nt++) {
      int bo_ = (nq * 64 + nt * 16 + l16) * 40 + lg * 8;
      fb_h[nt] = *reinterpret_cast<const short8*>(Bh + bo_);
      fb_l[nt] = *reinterpret_cast<const short8*>(Bl + bo_);
    }
#pragma unroll
    for (int mt = 0; mt < 4; mt++)
#pragma unroll
      for (int nt = 0; nt < 4; nt++) {
        acc[mt][nt] = __builtin_amdgcn_mfma_f32_16x16x32_bf16(fa_h[mt], fb_h[nt], acc[mt][nt], 0, 0, 0);
        acc[mt][nt] = __builtin_amdgcn_mfma_f32_16x16x32_bf16(fa_l[mt], fb_h[nt], acc[mt][nt], 0, 0, 0);
        acc[mt][nt] = __builtin_amdgcn_mfma_f32_16x16x32_bf16(fa_h[mt], fb_l[nt], acc[mt][nt], 0, 0, 0);
      }
    __syncthreads();
  }
#pragma unroll
  for (int nt = 0; nt < 4; nt++) {
    int n = n0 + nq * 64 + nt * 16 + l16;
    float bv = bias[n];
#pragma unroll
    for (int mt = 0; mt < 4; mt++) {
#pragma unroll
      for (int rr = 0; rr < 4; rr++) {
        int m = m0 + mq * 64 + mt * 16 + lg * 4 + rr;
        out[(size_t)m * CDIM + n] = acc[mt][nt][rr] + bv;
      }
    }
  }
}

// ---------------------------------------------------------------------------
extern "C" void kernel_launch(void* const* d_in, const int* in_sizes, int n_in,
                              void* d_out, int out_size, void* d_ws, size_t ws_size,
                              hipStream_t stream) {
  (void)in_sizes; (void)n_in; (void)out_size; (void)ws_size;
  const float* X    = (const float*)d_in[0];   // queries (4,4096,512)
  const float* Wqk  = (const float*)d_in[6];
  const float* Wv   = (const float*)d_in[7];
  const float* Wo   = (const float*)d_in[8];
  const float* bo   = (const float*)d_in[9];
  const float* rot  = (const float*)d_in[10];  // (64, 4, 32)

  // workspace layout (bytes), peak ~160 MB
  uint8_t* W = (uint8_t*)d_ws;
  float*    qk      = (float*)(W + 0);              // 33,554,432 B
  uint16_t* obuf    = (uint16_t*)(W + 33554432);    // 67,108,864 B
  uint16_t* qkhi    = (uint16_t*)(W + 100663296);   // 16,777,216 B
  uint16_t* qklo    = (uint16_t*)(W + 117440512);   // 16,777,216 B
  uint16_t* vhi     = (uint16_t*)(W + 134217728);   // 16,777,216 B
  int*      buckets = (int*)(W + 150994944);        //  2,097,152 B
  int*      st      = (int*)(W + 153092096);        //  2,097,152 B
  float*    lse     = (float*)(W + 155189248);      //  2,097,152 B
  float*    invn_g  = (float*)(W + 157286400);      //    524,288 B
  uint16_t* woT_hi  = (uint16_t*)(W + 157810688);   //    524,288 B
  uint16_t* woT_lo  = (uint16_t*)(W + 158334976);   //    524,288 B
  uint16_t* wvT0    = (uint16_t*)(W + 158859264);   //    524,288 B
  uint16_t* wvT1    = (uint16_t*)(W + 159383552);   // end 159,907,840
  // X planes alias obuf (dead until attn; gemm_v consumes them first)
  uint16_t* x0      = (uint16_t*)(W + 33554432);    // 16,777,216 B each
  uint16_t* x1      = (uint16_t*)(W + 50331648);
  uint16_t* comb_hi = (uint16_t*)(W + 0);           // alias qk (dead post-hash)
  uint16_t* comb_lo = (uint16_t*)(W + 16777216);

  hipLaunchKernelGGL(prep_kernel, dim3(9472), dim3(256), 0, stream,
                     X, Wv, Wo, x0, x1, wvT0, wvT1, woT_hi, woT_lo);
  hipLaunchKernelGGL(gemm_qk_kernel, dim3(256, 4), dim3(256), 0, stream,
                     X, Wqk, qk, qkhi, qklo, invn_g);
  hipLaunchKernelGGL(gemm_v_mfma_kernel, dim3(128, 4), dim3(512), 0, stream,
                     x0, x1, wvT0, wvT1, vhi);
  hipLaunchKernelGGL(hash_kernel, dim3(16, 32), dim3(256), 0, stream,
                     qk, rot, buckets);
  hipLaunchKernelGGL(sort_kernel, dim3(4, 32), dim3(256), 0, stream,
                     buckets, st);
  hipLaunchKernelGGL(attn_kernel, dim3(256, 32), dim3(256), 0, stream,
                     qkhi, qklo, vhi, invn_g, st, obuf, lse);
  hipLaunchKernelGGL(combine_kernel, dim3(32768), dim3(256), 0, stream,
                     obuf, lse, comb_hi, comb_lo);
  hipLaunchKernelGGL(gemm_out_kernel, dim3(128, 4), dim3(256), 0, stream,
                     comb_hi, comb_lo, woT_hi, woT_lo, bo, (float*)d_out);
}

// Round 11
// 417.973 us; speedup vs baseline: 1.1644x; 1.1644x over previous
//
#include <hip/hip_runtime.h>
#include <hip/hip_bf16.h>
#include <cstdint>
#include <cstddef>

// Problem constants (fixed by setup_inputs)
#define LSEQ   4096
#define DHD    64
#define NHASH  4
#define CDIM   512
#define NBH    32        // B*HEADS
#define MROWS  16384     // B*LSEQ
#define NCHUNK 256       // NHASH*LSEQ/64

typedef __attribute__((ext_vector_type(8))) short short8;
typedef __attribute__((ext_vector_type(4))) float f32x4;
typedef __attribute__((ext_vector_type(2))) float f32x2;

__device__ inline uint32_t f2bf(float f) {
  uint32_t u = __float_as_uint(f);
  return (u + 0x7FFFu + ((u >> 16) & 1u)) >> 16;
}
__device__ inline float bf2f(uint32_t h) { return __uint_as_float(h << 16); }
__device__ inline void split2(float f, uint32_t& hi, uint32_t& lo) {
  hi = f2bf(f);
  lo = f2bf(f - bf2f(hi));
}
// HW packed f32->bf16 (RNE, same bits as f2bf for normal values):
// low16 = bf16(a), high16 = bf16(b)
__device__ inline uint32_t cvtpk_bf16(float a, float b) {
  uint32_t r;
  asm("v_cvt_pk_bf16_f32 %0, %1, %2" : "=v"(r) : "v"(a), "v"(b));
  return r;
}
__device__ inline short8 ldsK(const uint16_t* p) {   // two b64 reads -> short8
  union { uint2 u[2]; short8 s; } t;
  t.u[0] = *reinterpret_cast<const uint2*>(p);
  t.u[1] = *reinterpret_cast<const uint2*>(p + 4);
  return t.s;
}

// ---------------------------------------------------------------------------
// K0: fused prep.  blocks [0,8192): X->2 bf16 planes; [8192,9216): Wo split+
// transpose; [9216,9472): Wv split+transpose.  UNCHANGED (r8-passing).
// ---------------------------------------------------------------------------
__global__ __launch_bounds__(256) void prep_kernel(
    const float* __restrict__ X, const float* __restrict__ Wv,
    const float* __restrict__ Wo,
    uint16_t* __restrict__ X0, uint16_t* __restrict__ X1,
    uint16_t* __restrict__ wvT0, uint16_t* __restrict__ wvT1,
    uint16_t* __restrict__ woT_hi, uint16_t* __restrict__ woT_lo)
{
  __shared__ float Ts[32][33];
  const int bid = blockIdx.x, tid = threadIdx.x;
  if (bid < 8192) {
    size_t i = ((size_t)bid * 256 + tid) * 4;
    float4 v = *reinterpret_cast<const float4*>(X + i);
    uint32_t h01 = cvtpk_bf16(v.x, v.y);
    uint32_t h23 = cvtpk_bf16(v.z, v.w);
    float r0 = v.x - __uint_as_float(h01 << 16);
    float r1 = v.y - __uint_as_float(h01 & 0xffff0000u);
    float r2 = v.z - __uint_as_float(h23 << 16);
    float r3 = v.w - __uint_as_float(h23 & 0xffff0000u);
    uint2 hw = {h01, h23};
    uint2 lw = {cvtpk_bf16(r0, r1), cvtpk_bf16(r2, r3)};
    *reinterpret_cast<uint2*>(X0 + i) = hw;
    *reinterpret_cast<uint2*>(X1 + i) = lw;
  } else if (bid < 9216) {
    int idx = (bid - 8192) * 256 + tid;   // k*512 + n
    int k = idx >> 9, n = idx & 511;
    uint32_t hi, lo;
    split2(Wo[idx], hi, lo);
    woT_hi[n * 512 + k] = (uint16_t)hi;
    woT_lo[n * 512 + k] = (uint16_t)lo;
  } else {
    int wb = bid - 9216;                  // 0..255
    const int k0 = (wb >> 4) * 32, n0 = (wb & 15) * 32;
#pragma unroll
    for (int i = 0; i < 4; i++) {
      int flat = i * 256 + tid;
      int r = flat >> 5, c = flat & 31;
      Ts[r][c] = Wv[(size_t)(k0 + r) * 512 + n0 + c];
    }
    __syncthreads();
#pragma unroll
    for (int i = 0; i < 4; i++) {
      int flat = i * 256 + tid;
      int nr = flat >> 5, kc = flat & 31;
      uint32_t h, l;
      split2(Ts[kc][nr], h, l);
      size_t idx = (size_t)(n0 + nr) * 512 + k0 + kc;
      wvT0[idx] = (uint16_t)h;
      wvT1[idx] = (uint16_t)l;
    }
  }
}

// ---------------------------------------------------------------------------
// K1a: qk projection GEMM — FROZEN MATH, FROZEN COMPILATION CONTEXT.
// r8-passing kernel VERBATIM as its own standalone __global__ (r10 lesson:
// merging into another kernel perturbs codegen and flips buckets).
// DO NOT TOUCH.  grid (128,4), block 512.
// ---------------------------------------------------------------------------
__global__ __launch_bounds__(512) void gemm_qk_kernel(
    const float* __restrict__ X, const float* __restrict__ Wqk,
    float* __restrict__ qk, uint16_t* __restrict__ qkhi,
    uint16_t* __restrict__ qklo, float* __restrict__ invn_g)
{
  const int m0 = blockIdx.x * 128;
  const int n0 = blockIdx.y * 128;
  __shared__ float As[32][132];   // [k][m]
  __shared__ float Bs[32][132];   // [k][n]
  const int tid = threadIdx.x;
  const int r = tid >> 5, c = tid & 31;   // rows 8r.., cols 4c..
  f32x2 acc2[8][2];
#pragma unroll
  for (int i = 0; i < 8; i++) {
    acc2[i][0] = {0.f, 0.f};
    acc2[i][1] = {0.f, 0.f};
  }

  const int arow = tid >> 2;        // 0..127
  const int ak   = (tid & 3) * 4;   // k sub-chunk
  const int brow = tid >> 4;        // 0..31
  const int bn   = (tid & 15) * 4;  // n sub-chunk

  float4 pa[2], pb[2];
  // prologue: load kb=0 tile
#pragma unroll
  for (int rr = 0; rr < 2; rr++) {
    pa[rr] = *reinterpret_cast<const float4*>(&X[(size_t)(m0 + arow) * CDIM + ak + rr * 16]);
    pb[rr] = *reinterpret_cast<const float4*>(&Wqk[(size_t)brow * CDIM + n0 + bn + rr * 64]);
  }

  for (int kb = 0; kb < CDIM; kb += 32) {
    // write staged regs to LDS
#pragma unroll
    for (int rr = 0; rr < 2; rr++) {
      As[ak + rr * 16 + 0][arow] = pa[rr].x;
      As[ak + rr * 16 + 1][arow] = pa[rr].y;
      As[ak + rr * 16 + 2][arow] = pa[rr].z;
      As[ak + rr * 16 + 3][arow] = pa[rr].w;
      *reinterpret_cast<float4*>(&Bs[brow][bn + rr * 64]) = pb[rr];
    }
    __syncthreads();
    // prefetch next tile into regs (overlaps with compute below)
    if (kb + 32 < CDIM) {
#pragma unroll
      for (int rr = 0; rr < 2; rr++) {
        pa[rr] = *reinterpret_cast<const float4*>(
            &X[(size_t)(m0 + arow) * CDIM + kb + 32 + ak + rr * 16]);
        pb[rr] = *reinterpret_cast<const float4*>(
            &Wqk[(size_t)(kb + 32 + brow) * CDIM + n0 + bn + rr * 64]);
      }
    }
#pragma unroll
    for (int k = 0; k < 32; k++) {
      float4 a0 = *reinterpret_cast<const float4*>(&As[k][r * 8]);
      float4 a1 = *reinterpret_cast<const float4*>(&As[k][r * 8 + 4]);
      float4 b  = *reinterpret_cast<const float4*>(&Bs[k][c * 4]);
      float am[8] = {a0.x, a0.y, a0.z, a0.w, a1.x, a1.y, a1.z, a1.w};
      f32x2 b01 = {b.x, b.y};
      f32x2 b23 = {b.z, b.w};
#pragma unroll
      for (int i = 0; i < 8; i++) {
        f32x2 av = {am[i], am[i]};
        acc2[i][0] += av * b01;   // fmuladd per component, k-ascending chain
        acc2[i][1] += av * b23;
      }
    }
    __syncthreads();
  }
  // epilogue: rows m0+r*8+ii, cols n0 + c*4 (head = (n0>>6)+(c>>4))
  const int head = (n0 >> 6) + (c >> 4);
#pragma unroll
  for (int ii = 0; ii < 8; ii++) {
    int m = m0 + r * 8 + ii;
    int b = m >> 12, t = m & 4095;
    size_t base = ((size_t)(b * 8 + head) * LSEQ + t) * DHD + (c & 15) * 4;
    float4 ov = {acc2[ii][0][0], acc2[ii][0][1], acc2[ii][1][0], acc2[ii][1][1]};
    *reinterpret_cast<float4*>(&qk[base]) = ov;
    uint32_t h0 = cvtpk_bf16(ov.x, ov.y);
    uint32_t h1 = cvtpk_bf16(ov.z, ov.w);
    float r0 = ov.x - __uint_as_float(h0 << 16);
    float r1 = ov.y - __uint_as_float(h0 & 0xffff0000u);
    float r2 = ov.z - __uint_as_float(h1 << 16);
    float r3 = ov.w - __uint_as_float(h1 & 0xffff0000u);
    *reinterpret_cast<uint2*>(&qkhi[base]) = {h0, h1};
    *reinterpret_cast<uint2*>(&qklo[base]) = {cvtpk_bf16(r0, r1), cvtpk_bf16(r2, r3)};
    float ss = ov.x * ov.x + ov.y * ov.y + ov.z * ov.z + ov.w * ov.w;
    ss += __shfl_xor(ss, 1, 64);
    ss += __shfl_xor(ss, 2, 64);
    ss += __shfl_xor(ss, 4, 64);
    ss += __shfl_xor(ss, 8, 64);
    if ((c & 15) == 0)
      invn_g[(size_t)(b * 8 + head) * LSEQ + t] = 1.0f / fmaxf(sqrtf(ss), 1e-12f);
  }
}

// ---------------------------------------------------------------------------
// K1b: v projection via bf16-split MFMA (3-term).  UNCHANGED (r8-passing).
// ---------------------------------------------------------------------------
__global__ __launch_bounds__(512) void gemm_v_mfma_kernel(
    const uint16_t* __restrict__ X0g, const uint16_t* __restrict__ X1g,
    const uint16_t* __restrict__ Wv0, const uint16_t* __restrict__ Wv1,
    uint16_t* __restrict__ vhi)
{
  __shared__ __align__(16) uint16_t Xs[2 * 128 * 40];
  __shared__ __align__(16) uint16_t Ws[2 * 128 * 40];
  const int tid = threadIdx.x;
  const int m0 = blockIdx.x * 128;
  const int n0 = blockIdx.y * 128;
  const int lane = tid & 63, w = tid >> 6;
  const int l16 = lane & 15, lg = lane >> 4;

  f32x4 acc[8];
#pragma unroll
  for (int nt = 0; nt < 8; nt++) acc[nt] = {0.f, 0.f, 0.f, 0.f};

  const int srow = tid >> 3;
  const int sch = (tid & 7) * 4;

  for (int kb = 0; kb < CDIM; kb += 32) {
#pragma unroll
    for (int i = 0; i < 4; i++) {
      int p = i >> 1;
      int row = (i & 1) * 64 + srow;
      const uint16_t* xg = (p == 0) ? X0g : X1g;
      const uint16_t* wg = (p == 0) ? Wv0 : Wv1;
      *reinterpret_cast<uint2*>(Xs + p * 5120 + row * 40 + sch) =
          *reinterpret_cast<const uint2*>(xg + (size_t)(m0 + row) * 512 + kb + sch);
      *reinterpret_cast<uint2*>(Ws + p * 5120 + row * 40 + sch) =
          *reinterpret_cast<const uint2*>(wg + (size_t)(n0 + row) * 512 + kb + sch);
    }
    __syncthreads();

    const int abase = (w * 16 + l16) * 40 + lg * 8;
    short8 a0 = *reinterpret_cast<const short8*>(Xs + abase);
    short8 a1 = *reinterpret_cast<const short8*>(Xs + 5120 + abase);
#pragma unroll
    for (int nt = 0; nt < 8; nt++) {
      int bbase = (nt * 16 + l16) * 40 + lg * 8;
      short8 b0 = *reinterpret_cast<const short8*>(Ws + bbase);
      short8 b1 = *reinterpret_cast<const short8*>(Ws + 5120 + bbase);
      acc[nt] = __builtin_amdgcn_mfma_f32_16x16x32_bf16(a0, b0, acc[nt], 0, 0, 0);
      acc[nt] = __builtin_amdgcn_mfma_f32_16x16x32_bf16(a1, b0, acc[nt], 0, 0, 0);
      acc[nt] = __builtin_amdgcn_mfma_f32_16x16x32_bf16(a0, b1, acc[nt], 0, 0, 0);
    }
    __syncthreads();
  }

#pragma unroll
  for (int rr = 0; rr < 4; rr++) {
    int mg = m0 + w * 16 + lg * 4 + rr;
    int b = mg >> 12, t = mg & 4095;
#pragma unroll
    for (int nt = 0; nt < 8; nt++) {
      int head = (n0 >> 6) + (nt >> 2);
      size_t base = ((size_t)(b * 8 + head) * LSEQ + t) * DHD + (nt & 3) * 16 + l16;
      vhi[base] = (uint16_t)cvtpk_bf16(acc[nt][rr], acc[nt][rr]);
    }
  }
}

// ---------------------------------------------------------------------------
// K2: LSH hashing.  UNCHANGED (bucket determinism; reads frozen f32 qk).
// ---------------------------------------------------------------------------
__global__ __launch_bounds__(256) void hash_kernel(
    const float* __restrict__ qk, const float* __restrict__ rot,
    int* __restrict__ buckets)
{
  __shared__ float rotT[128][68];   // [h*32+i][f]
  const int tid = threadIdx.x;
  for (int idx = tid; idx < 64 * 128; idx += 256) {
    int f = idx >> 7, hi = idx & 127;
    rotT[hi][f] = rot[idx];
  }
  __syncthreads();
  const int bh = blockIdx.y;
  const int t = blockIdx.x * 256 + tid;
  float4 row4[16];
  const float* src = &qk[((size_t)bh * LSEQ + t) * DHD];
#pragma unroll
  for (int i = 0; i < 16; i++) row4[i] = reinterpret_cast<const float4*>(src)[i];

  int* bout = &buckets[(size_t)bh * NHASH * LSEQ];
  for (int h = 0; h < NHASH; h++) {
    float rc[32];
    float best = -3.0e38f;
    int bidx = 0;
#pragma unroll 4
    for (int i = 0; i < 32; i++) {
      const float* rr = &rotT[h * 32 + i][0];
      float a = 0.f;
#pragma unroll
      for (int f4 = 0; f4 < 16; f4++) {
        float4 rv = reinterpret_cast<const float4*>(rr)[f4];
        a += row4[f4].x * rv.x + row4[f4].y * rv.y + row4[f4].z * rv.z + row4[f4].w * rv.w;
      }
      rc[i] = a;
      if (a > best) { best = a; bidx = i; }
    }
#pragma unroll
    for (int i = 0; i < 32; i++) {
      float nv = -rc[i];
      if (nv > best) { best = nv; bidx = 32 + i; }
    }
    bout[h * LSEQ + t] = bidx;
  }
}

// ---------------------------------------------------------------------------
// K3: stable counting sort per (bh, h).  Rank loop replaced by 6-round
// ballot multi-split — EXACT integer logic, st bitwise-identical, ~10x
// fewer VALU ops than the 64-iter shfl loop.
// ---------------------------------------------------------------------------
__global__ __launch_bounds__(256) void sort_kernel(
    const int* __restrict__ buckets, int* __restrict__ st)
{
  __shared__ int hist[64][64];
  const int h = blockIdx.x, bh = blockIdx.y;
  const int tid = threadIdx.x;
  const int* bk = &buckets[((size_t)bh * NHASH + h) * LSEQ];

  for (int i = tid; i < 64 * 64; i += 256) (&hist[0][0])[i] = 0;
  __syncthreads();
  for (int t = tid; t < LSEQ; t += 256) {
    int b = bk[t];
    atomicAdd(&hist[t >> 6][b], 1);
  }
  __syncthreads();
  if (tid < 64) {
    int tot = 0;
    for (int s = 0; s < 64; s++) tot += hist[s][tid];
    int vsc = tot;
    for (int off = 1; off < 64; off <<= 1) {
      int nv = __shfl_up(vsc, off, 64);
      if (tid >= off) vsc += nv;
    }
    int run = h * LSEQ + (vsc - tot);
    for (int s = 0; s < 64; s++) {
      int tmp = hist[s][tid];
      hist[s][tid] = run;
      run += tmp;
    }
  }
  __syncthreads();
  const int wave = tid >> 6, lane = tid & 63;
  const uint64_t below = (lane == 63) ? 0x7fffffffffffffffull
                                      : ((1ull << lane) - 1ull);
  for (int si = 0; si < 16; si++) {
    int seg = wave * 16 + si;
    int pos = seg * 64 + lane;
    int b = bk[pos];
    // multi-split: mask of lanes whose 6-bit bucket equals mine
    uint64_t same = ~0ull;
#pragma unroll
    for (int j = 0; j < 6; j++) {
      uint64_t bal = __ballot((b >> j) & 1);
      same &= ((b >> j) & 1) ? bal : ~bal;
    }
    int rank = __popcll(same & below);
    int dest = hist[seg][b] + rank;
    st[(size_t)bh * (NHASH * LSEQ) + dest] = pos;
  }
}

// ---------------------------------------------------------------------------
// K4: chunked attention.  r8-passing version + s_setprio(1) around the two
// MFMA clusters (T5: pure scheduler hint, phase-diverse blocks; no math
// change).
// ---------------------------------------------------------------------------
__global__ __launch_bounds__(256) void attn_kernel(
    const uint16_t* __restrict__ qkhi, const uint16_t* __restrict__ qklo,
    const uint16_t* __restrict__ vhi, const float* __restrict__ invn_g,
    const int* __restrict__ st, uint16_t* __restrict__ o,
    float* __restrict__ lse_out)
{
  __shared__ __align__(16) uint8_t smem[53248];
  uint16_t* Khi  = (uint16_t*)smem;                  // [128][68] = 17408 B
  uint16_t* Klo  = Khi + 128 * 68;                   // +17408 B
  uint16_t* Vthi = (uint16_t*)(smem + 34816);        // [64][128] = 16384 B
  float*    invn = (float*)(smem + 52224);           // 128 f
  int*      kpos = (int*)(smem + 52736);             // 128 i
  uint32_t* P32  = (uint32_t*)smem;                  // [64][132] u32, alias K

  // XCD-aware swizzle: lin -> (xcd, idx); each XCD gets 4 bh x 256 chunks
  const int lin = blockIdx.y * 256 + blockIdx.x;
  const int xcd = lin & 7, sidx = lin >> 3;
  const int bh = (xcd << 2) | (sidx >> 8);
  const int cchunk = sidx & 255;

  const int tid = threadIdx.x;
  const int prev = (cchunk + NCHUNK - 1) & (NCHUNK - 1);
  const int* stb = &st[(size_t)bh * (NHASH * LSEQ)];
  const int h = cchunk >> 6;

  if (tid < 128) {
    int kp = (tid < 64) ? stb[prev * 64 + tid] : stb[cchunk * 64 + (tid - 64)];
    kpos[tid] = kp;
    invn[tid] = invn_g[(size_t)bh * LSEQ + kp];
  }
  __syncthreads();

  // ---- stage K planes (pure copies) ----
  {
    const int d4 = tid & 15, rbase = tid >> 4;
    const uint16_t* qhb = qkhi + (size_t)bh * LSEQ * DHD;
    const uint16_t* qlb = qklo + (size_t)bh * LSEQ * DHD;
#pragma unroll
    for (int it = 0; it < 8; it++) {
      int row = rbase + it * 16;
      size_t src = (size_t)kpos[row] * DHD + d4 * 4;
      *reinterpret_cast<uint2*>(Khi + row * 68 + d4 * 4) =
          *reinterpret_cast<const uint2*>(qhb + src);
      *reinterpret_cast<uint2*>(Klo + row * 68 + d4 * 4) =
          *reinterpret_cast<const uint2*>(qlb + src);
    }
  }
  // ---- stage V transposed (u16 4x4 transpose), swizzled ----
  {
    const int d4 = tid & 15, jg0 = tid >> 4;
    const uint16_t* vb = vhi + (size_t)bh * LSEQ * DHD;
#pragma unroll
    for (int half = 0; half < 2; half++) {
      int jg = jg0 + half * 16;   // 0..31, j = 4*jg..4*jg+3
      uint2 vr[4];
#pragma unroll
      for (int s = 0; s < 4; s++)
        vr[s] = *reinterpret_cast<const uint2*>(vb + (size_t)kpos[jg * 4 + s] * DHD + d4 * 4);
#pragma unroll
      for (int i = 0; i < 4; i++) {
        int d = d4 * 4 + i;
        uint32_t e0 = (((i & 2) ? vr[0].y : vr[0].x) >> ((i & 1) * 16)) & 0xffffu;
        uint32_t e1 = (((i & 2) ? vr[1].y : vr[1].x) >> ((i & 1) * 16)) & 0xffffu;
        uint32_t e2 = (((i & 2) ? vr[2].y : vr[2].x) >> ((i & 1) * 16)) & 0xffffu;
        uint32_t e3 = (((i & 2) ? vr[3].y : vr[3].x) >> ((i & 1) * 16)) & 0xffffu;
        uint2 outw = {e0 | (e1 << 16), e2 | (e3 << 16)};
        int cpr = (jg >> 1) ^ (d & 15);
        *reinterpret_cast<uint2*>(Vthi + d * 128 + cpr * 8 + (jg & 1) * 4) = outw;
      }
    }
  }
  __syncthreads();

  const int lane = tid & 63, w = tid >> 6;
  const int l16 = lane & 15, lg = lane >> 4;

  // ---- QK^T (bf16x3), wave w -> q-rows 16w..16w+15 ----
  f32x4 acc[8];
#pragma unroll
  for (int nt = 0; nt < 8; nt++) acc[nt] = {0.f, 0.f, 0.f, 0.f};

  __builtin_amdgcn_s_setprio(1);
#pragma unroll
  for (int ks = 0; ks < 2; ks++) {
    int aoff = (64 + w * 16 + l16) * 68 + ks * 32 + lg * 8;
    short8 a_hi = ldsK(Khi + aoff);
    short8 a_lo = ldsK(Klo + aoff);
#pragma unroll
    for (int nt = 0; nt < 8; nt++) {
      int boff = (nt * 16 + l16) * 68 + ks * 32 + lg * 8;
      short8 b_hi = ldsK(Khi + boff);
      short8 b_lo = ldsK(Klo + boff);
      acc[nt] = __builtin_amdgcn_mfma_f32_16x16x32_bf16(a_hi, b_hi, acc[nt], 0, 0, 0);
      acc[nt] = __builtin_amdgcn_mfma_f32_16x16x32_bf16(a_lo, b_hi, acc[nt], 0, 0, 0);
      acc[nt] = __builtin_amdgcn_mfma_f32_16x16x32_bf16(a_hi, b_lo, acc[nt], 0, 0, 0);
    }
  }
  __builtin_amdgcn_s_setprio(0);

  // ---- register softmax on the D-layout ----
  float invc[8]; int kpc[8];
#pragma unroll
  for (int nt = 0; nt < 8; nt++) {
    invc[nt] = invn[nt * 16 + l16] * 0.125f;
    kpc[nt] = kpos[nt * 16 + l16];
  }
  float pll[4];
#pragma unroll
  for (int r = 0; r < 4; r++) {
    int q = w * 16 + lg * 4 + r;
    int qp = kpos[64 + q];
    float mm = -3.0e38f;
#pragma unroll
    for (int nt = 0; nt < 8; nt++) {
      float s = acc[nt][r] * invc[nt];
      if (qp == kpc[nt]) s = -5e4f;
      acc[nt][r] = s;
      mm = fmaxf(mm, s);
    }
    mm = fmaxf(mm, __shfl_xor(mm, 1, 64));
    mm = fmaxf(mm, __shfl_xor(mm, 2, 64));
    mm = fmaxf(mm, __shfl_xor(mm, 4, 64));
    mm = fmaxf(mm, __shfl_xor(mm, 8, 64));
    float ll = 0.f;
#pragma unroll
    for (int nt = 0; nt < 8; nt++) {
      float p = __expf(acc[nt][r] - mm);
      acc[nt][r] = p;
      ll += p;
    }
    ll += __shfl_xor(ll, 1, 64);
    ll += __shfl_xor(ll, 2, 64);
    ll += __shfl_xor(ll, 4, 64);
    ll += __shfl_xor(ll, 8, 64);
    if (l16 == 0)
      lse_out[(size_t)bh * (NHASH * LSEQ) + h * LSEQ + qp] = mm + __logf(ll);
    pll[r] = 1.0f / ll;
  }
  __syncthreads();   // all K-plane reads done; safe to alias P32

  // ---- write P (packed hi|lo u32, via cvt_pk) ----
#pragma unroll
  for (int r = 0; r < 4; r++) {
    int q = w * 16 + lg * 4 + r;
#pragma unroll
    for (int nt = 0; nt < 8; nt++) {
      float p = acc[nt][r];
      uint32_t t1 = cvtpk_bf16(p, p);
      float res = p - __uint_as_float(t1 << 16);
      P32[q * 132 + nt * 16 + l16] = cvtpk_bf16(p, res);   // low=phi, high=plo
    }
  }
  // no barrier: wave reads back only its own 16 P rows

  // ---- PV: O = P.Vhi (2-term) ----
  f32x4 oacc[4];
#pragma unroll
  for (int nt = 0; nt < 4; nt++) oacc[nt] = {0.f, 0.f, 0.f, 0.f};

  __builtin_amdgcn_s_setprio(1);
#pragma unroll
  for (int ks = 0; ks < 4; ks++) {
    const uint32_t* pr = P32 + (w * 16 + l16) * 132 + ks * 32 + lg * 8;
    uint4 ua = *reinterpret_cast<const uint4*>(pr);
    uint4 ub = *reinterpret_cast<const uint4*>(pr + 4);
    uint32_t u[8] = {ua.x, ua.y, ua.z, ua.w, ub.x, ub.y, ub.z, ub.w};
    union { uint32_t w4[4]; short8 s8; } ph, pl;
#pragma unroll
    for (int k2 = 0; k2 < 4; k2++) {
      ph.w4[k2] = (u[2 * k2] & 0xffffu) | (u[2 * k2 + 1] << 16);
      pl.w4[k2] = (u[2 * k2] >> 16) | (u[2 * k2 + 1] & 0xffff0000u);
    }
    const int cc = ks * 4 + lg;
#pragma unroll
    for (int nt = 0; nt < 4; nt++) {
      int voff = (nt * 16 + l16) * 128 + ((cc ^ l16) & 15) * 8;
      short8 v_hi = *reinterpret_cast<const short8*>(Vthi + voff);
      oacc[nt] = __builtin_amdgcn_mfma_f32_16x16x32_bf16(ph.s8, v_hi, oacc[nt], 0, 0, 0);
      oacc[nt] = __builtin_amdgcn_mfma_f32_16x16x32_bf16(pl.s8, v_hi, oacc[nt], 0, 0, 0);
    }
  }
  __builtin_amdgcn_s_setprio(0);

  // ---- normalize + write O (bf16, unsorted) ----
  {
    uint16_t* ob = o + ((size_t)bh * (NHASH * LSEQ) + (size_t)h * LSEQ) * DHD;
#pragma unroll
    for (int r = 0; r < 4; r++) {
      int q = w * 16 + lg * 4 + r;
      int qp = kpos[64 + q];
      float s = pll[r];
#pragma unroll
      for (int nt = 0; nt < 4; nt++) {
        float v = oacc[nt][r] * s;
        ob[(size_t)qp * DHD + nt * 16 + l16] = (uint16_t)cvtpk_bf16(v, v);
      }
    }
  }
}

// ---------------------------------------------------------------------------
// K5: combine hash rounds -> comb bf16 hi/lo planes (cvt_pk).  UNCHANGED.
// ---------------------------------------------------------------------------
__global__ __launch_bounds__(256) void combine_kernel(
    const uint16_t* __restrict__ o, const float* __restrict__ lse,
    uint16_t* __restrict__ comb_hi, uint16_t* __restrict__ comb_lo)
{
  int gid = blockIdx.x * 4 + (threadIdx.x >> 6);
  int lane = threadIdx.x & 63;
  int bh = gid >> 12;
  int pos = gid & 4095;
  const float* lb = &lse[(size_t)bh * (NHASH * LSEQ) + pos];
  float l0 = lb[0], l1 = lb[LSEQ], l2 = lb[2 * LSEQ], l3 = lb[3 * LSEQ];
  float m = fmaxf(fmaxf(l0, l1), fmaxf(l2, l3));
  float w0 = __expf(l0 - m), w1 = __expf(l1 - m), w2 = __expf(l2 - m), w3 = __expf(l3 - m);
  float inv = 1.0f / (w0 + w1 + w2 + w3);
  const uint16_t* ob = &o[((size_t)bh * (NHASH * LSEQ) + pos) * DHD];
  float val = (w0 * bf2f(ob[lane]) + w1 * bf2f(ob[(size_t)LSEQ * DHD + lane]) +
               w2 * bf2f(ob[(size_t)2 * LSEQ * DHD + lane]) +
               w3 * bf2f(ob[(size_t)3 * LSEQ * DHD + lane])) * inv;
  int b = bh >> 3, head = bh & 7;
  size_t idx = ((size_t)(b * LSEQ + pos)) * CDIM + head * DHD + lane;
  uint32_t hw = cvtpk_bf16(val, val);
  float res = val - __uint_as_float(hw << 16);
  comb_hi[idx] = (uint16_t)hw;
  comb_lo[idx] = (uint16_t)cvtpk_bf16(res, res);
}

// ---------------------------------------------------------------------------
// K6: output GEMM, bf16x3 MFMA.  UNCHANGED.
// ---------------------------------------------------------------------------
__global__ __launch_bounds__(256) void gemm_out_kernel(
    const uint16_t* __restrict__ Ahi_g, const uint16_t* __restrict__ Alo_g,
    const uint16_t* __restrict__ Bhi_g, const uint16_t* __restrict__ Blo_g,
    const float* __restrict__ bias, float* __restrict__ out)
{
  __shared__ __align__(16) uint16_t Ah[128 * 40];
  __shared__ __align__(16) uint16_t Al[128 * 40];
  __shared__ __align__(16) uint16_t Bh[128 * 40];
  __shared__ __align__(16) uint16_t Bl[128 * 40];
  const int tid = threadIdx.x;
  const int m0 = blockIdx.x * 128, n0 = blockIdx.y * 128;
  const int lane = tid & 63, w = tid >> 6;
  const int l16 = lane & 15, lg = lane >> 4;
  const int mq = w >> 1, nq = w & 1;
  f32x4 acc[4][4];
#pragma unroll
  for (int i = 0; i < 4; i++)
#pragma unroll
    for (int j = 0; j < 4; j++) acc[i][j] = {0.f, 0.f, 0.f, 0.f};

  const int srow = tid >> 1, sh = tid & 1;
  for (int kb = 0; kb < CDIM; kb += 32) {
    {
      const uint4* sa_h = (const uint4*)(Ahi_g + (size_t)(m0 + srow) * CDIM + kb + sh * 16);
      const uint4* sa_l = (const uint4*)(Alo_g + (size_t)(m0 + srow) * CDIM + kb + sh * 16);
      const uint4* sb_h = (const uint4*)(Bhi_g + (size_t)(n0 + srow) * CDIM + kb + sh * 16);
      const uint4* sb_l = (const uint4*)(Blo_g + (size_t)(n0 + srow) * CDIM + kb + sh * 16);
      uint4* da_h = (uint4*)(Ah + srow * 40 + sh * 16);
      uint4* da_l = (uint4*)(Al + srow * 40 + sh * 16);
      uint4* db_h = (uint4*)(Bh + srow * 40 + sh * 16);
      uint4* db_l = (uint4*)(Bl + srow * 40 + sh * 16);
      da_h[0] = sa_h[0]; da_h[1] = sa_h[1];
      da_l[0] = sa_l[0]; da_l[1] = sa_l[1];
      db_h[0] = sb_h[0]; db_h[1] = sb_h[1];
      db_l[0] = sb_l[0]; db_l[1] = sb_l[1];
    }
    __syncthreads();
    short8 fa_h[4], fa_l[4], fb_h[4], fb_l[4];
#pragma unroll
    for (int mt = 0; mt < 4; mt++) {
      int ao = (mq * 64 + mt * 16 + l16) * 40 + lg * 8;
      fa_h[mt] = *reinterpret_cast<const short8*>(Ah + ao);
      fa_l[mt] = *reinterpret_cast<const short8*>(Al + ao);
    }
#pragma unroll
    for (int nt = 0; nt < 4; nt++) {
      int bo_ = (nq * 64 + nt * 16 + l16) * 40 + lg * 8;
      fb_h[nt] = *reinterpret_cast<const short8*>(Bh + bo_);
      fb_l[nt] = *reinterpret_cast<const short8*>(Bl + bo_);
    }
#pragma unroll
    for (int mt = 0; mt < 4; mt++)
#pragma unroll
      for (int nt = 0; nt < 4; nt++) {
        acc[mt][nt] = __builtin_amdgcn_mfma_f32_16x16x32_bf16(fa_h[mt], fb_h[nt], acc[mt][nt], 0, 0, 0);
        acc[mt][nt] = __builtin_amdgcn_mfma_f32_16x16x32_bf16(fa_l[mt], fb_h[nt], acc[mt][nt], 0, 0, 0);
        acc[mt][nt] = __builtin_amdgcn_mfma_f32_16x16x32_bf16(fa_h[mt], fb_l[nt], acc[mt][nt], 0, 0, 0);
      }
    __syncthreads();
  }
#pragma unroll
  for (int nt = 0; nt < 4; nt++) {
    int n = n0 + nq * 64 + nt * 16 + l16;
    float bv = bias[n];
#pragma unroll
    for (int mt = 0; mt < 4; mt++) {
#pragma unroll
      for (int rr = 0; rr < 4; rr++) {
        int m = m0 + mq * 64 + mt * 16 + lg * 4 + rr;
        out[(size_t)m * CDIM + n] = acc[mt][nt][rr] + bv;
      }
    }
  }
}

// ---------------------------------------------------------------------------
extern "C" void kernel_launch(void* const* d_in, const int* in_sizes, int n_in,
                              void* d_out, int out_size, void* d_ws, size_t ws_size,
                              hipStream_t stream) {
  (void)in_sizes; (void)n_in; (void)out_size; (void)ws_size;
  const float* X    = (const float*)d_in[0];   // queries (4,4096,512)
  const float* Wqk  = (const float*)d_in[6];
  const float* Wv   = (const float*)d_in[7];
  const float* Wo   = (const float*)d_in[8];
  const float* bo   = (const float*)d_in[9];
  const float* rot  = (const float*)d_in[10];  // (64, 4, 32)

  // workspace layout (bytes), peak ~160 MB
  uint8_t* W = (uint8_t*)d_ws;
  float*    qk      = (float*)(W + 0);              // 33,554,432 B
  uint16_t* obuf    = (uint16_t*)(W + 33554432);    // 67,108,864 B
  uint16_t* qkhi    = (uint16_t*)(W + 100663296);   // 16,777,216 B
  uint16_t* qklo    = (uint16_t*)(W + 117440512);   // 16,777,216 B
  uint16_t* vhi     = (uint16_t*)(W + 134217728);   // 16,777,216 B
  int*      buckets = (int*)(W + 150994944);        //  2,097,152 B
  int*      st      = (int*)(W + 153092096);        //  2,097,152 B
  float*    lse     = (float*)(W + 155189248);      //  2,097,152 B
  float*    invn_g  = (float*)(W + 157286400);      //    524,288 B
  uint16_t* woT_hi  = (uint16_t*)(W + 157810688);   //    524,288 B
  uint16_t* woT_lo  = (uint16_t*)(W + 158334976);   //    524,288 B
  uint16_t* wvT0    = (uint16_t*)(W + 158859264);   //    524,288 B
  uint16_t* wvT1    = (uint16_t*)(W + 159383552);   // end 159,907,840
  // X planes alias obuf (dead until attn; gemm_v consumes them first)
  uint16_t* x0      = (uint16_t*)(W + 33554432);    // 16,777,216 B each
  uint16_t* x1      = (uint16_t*)(W + 50331648);
  uint16_t* comb_hi = (uint16_t*)(W + 0);           // alias qk (dead post-hash)
  uint16_t* comb_lo = (uint16_t*)(W + 16777216);

  hipLaunchKernelGGL(prep_kernel, dim3(9472), dim3(256), 0, stream,
                     X, Wv, Wo, x0, x1, wvT0, wvT1, woT_hi, woT_lo);
  hipLaunchKernelGGL(gemm_qk_kernel, dim3(128, 4), dim3(512), 0, stream,
                     X, Wqk, qk, qkhi, qklo, invn_g);
  hipLaunchKernelGGL(gemm_v_mfma_kernel, dim3(128, 4), dim3(512), 0, stream,
                     x0, x1, wvT0, wvT1, vhi);
  hipLaunchKernelGGL(hash_kernel, dim3(16, 32), dim3(256), 0, stream,
                     qk, rot, buckets);
  hipLaunchKernelGGL(sort_kernel, dim3(4, 32), dim3(256), 0, stream,
                     buckets, st);
  hipLaunchKernelGGL(attn_kernel, dim3(256, 32), dim3(256), 0, stream,
                     qkhi, qklo, vhi, invn_g, st, obuf, lse);
  hipLaunchKernelGGL(combine_kernel, dim3(32768), dim3(256), 0, stream,
                     obuf, lse, comb_hi, comb_lo);
  hipLaunchKernelGGL(gemm_out_kernel, dim3(128, 4), dim3(256), 0, stream,
                     comb_hi, comb_lo, woT_hi, woT_lo, bo, (float*)d_out);
}

// Round 12
// 415.471 us; speedup vs baseline: 1.1714x; 1.0060x over previous
//
#include <hip/hip_runtime.h>
#include <hip/hip_bf16.h>
#include <cstdint>
#include <cstddef>

// Problem constants (fixed by setup_inputs)
#define LSEQ   4096
#define DHD    64
#define NHASH  4
#define CDIM   512
#define NBH    32        // B*HEADS
#define MROWS  16384     // B*LSEQ
#define NCHUNK 256       // NHASH*LSEQ/64

typedef __attribute__((ext_vector_type(8))) short short8;
typedef __attribute__((ext_vector_type(4))) float f32x4;
typedef __attribute__((ext_vector_type(2))) float f32x2;

__device__ inline uint32_t f2bf(float f) {
  uint32_t u = __float_as_uint(f);
  return (u + 0x7FFFu + ((u >> 16) & 1u)) >> 16;
}
__device__ inline float bf2f(uint32_t h) { return __uint_as_float(h << 16); }
__device__ inline void split2(float f, uint32_t& hi, uint32_t& lo) {
  hi = f2bf(f);
  lo = f2bf(f - bf2f(hi));
}
// HW packed f32->bf16 (RNE, same bits as f2bf for normal values):
// low16 = bf16(a), high16 = bf16(b)
__device__ inline uint32_t cvtpk_bf16(float a, float b) {
  uint32_t r;
  asm("v_cvt_pk_bf16_f32 %0, %1, %2" : "=v"(r) : "v"(a), "v"(b));
  return r;
}
__device__ inline short8 ldsK(const uint16_t* p) {   // two b64 reads -> short8
  union { uint2 u[2]; short8 s; } t;
  t.u[0] = *reinterpret_cast<const uint2*>(p);
  t.u[1] = *reinterpret_cast<const uint2*>(p + 4);
  return t.s;
}

// ---------------------------------------------------------------------------
// K0: prep (weights only — X split now inlined in gemm_v).
// blocks [0,1024): Wo split+transpose; [1024,1280): Wv split+transpose.
// ---------------------------------------------------------------------------
__global__ __launch_bounds__(256) void prep_kernel(
    const float* __restrict__ Wv, const float* __restrict__ Wo,
    uint16_t* __restrict__ wvT0, uint16_t* __restrict__ wvT1,
    uint16_t* __restrict__ woT_hi, uint16_t* __restrict__ woT_lo)
{
  __shared__ float Ts[32][33];
  const int bid = blockIdx.x, tid = threadIdx.x;
  if (bid < 1024) {
    int idx = bid * 256 + tid;   // k*512 + n
    int k = idx >> 9, n = idx & 511;
    uint32_t hi, lo;
    split2(Wo[idx], hi, lo);
    woT_hi[n * 512 + k] = (uint16_t)hi;
    woT_lo[n * 512 + k] = (uint16_t)lo;
  } else {
    int wb = bid - 1024;                  // 0..255
    const int k0 = (wb >> 4) * 32, n0 = (wb & 15) * 32;
#pragma unroll
    for (int i = 0; i < 4; i++) {
      int flat = i * 256 + tid;
      int r = flat >> 5, c = flat & 31;
      Ts[r][c] = Wv[(size_t)(k0 + r) * 512 + n0 + c];
    }
    __syncthreads();
#pragma unroll
    for (int i = 0; i < 4; i++) {
      int flat = i * 256 + tid;
      int nr = flat >> 5, kc = flat & 31;
      uint32_t h, l;
      split2(Ts[kc][nr], h, l);
      size_t idx = (size_t)(n0 + nr) * 512 + k0 + kc;
      wvT0[idx] = (uint16_t)h;
      wvT1[idx] = (uint16_t)l;
    }
  }
}

// ---------------------------------------------------------------------------
// K1a: qk projection GEMM — FROZEN MATH, FROZEN COMPILATION CONTEXT.
// r8/r11-passing kernel VERBATIM as its own standalone __global__ (r10
// lesson: merging into another kernel perturbs codegen and flips buckets).
// DO NOT TOUCH.  grid (128,4), block 512.
// ---------------------------------------------------------------------------
__global__ __launch_bounds__(512) void gemm_qk_kernel(
    const float* __restrict__ X, const float* __restrict__ Wqk,
    float* __restrict__ qk, uint16_t* __restrict__ qkhi,
    uint16_t* __restrict__ qklo, float* __restrict__ invn_g)
{
  const int m0 = blockIdx.x * 128;
  const int n0 = blockIdx.y * 128;
  __shared__ float As[32][132];   // [k][m]
  __shared__ float Bs[32][132];   // [k][n]
  const int tid = threadIdx.x;
  const int r = tid >> 5, c = tid & 31;   // rows 8r.., cols 4c..
  f32x2 acc2[8][2];
#pragma unroll
  for (int i = 0; i < 8; i++) {
    acc2[i][0] = {0.f, 0.f};
    acc2[i][1] = {0.f, 0.f};
  }

  const int arow = tid >> 2;        // 0..127
  const int ak   = (tid & 3) * 4;   // k sub-chunk
  const int brow = tid >> 4;        // 0..31
  const int bn   = (tid & 15) * 4;  // n sub-chunk

  float4 pa[2], pb[2];
  // prologue: load kb=0 tile
#pragma unroll
  for (int rr = 0; rr < 2; rr++) {
    pa[rr] = *reinterpret_cast<const float4*>(&X[(size_t)(m0 + arow) * CDIM + ak + rr * 16]);
    pb[rr] = *reinterpret_cast<const float4*>(&Wqk[(size_t)brow * CDIM + n0 + bn + rr * 64]);
  }

  for (int kb = 0; kb < CDIM; kb += 32) {
    // write staged regs to LDS
#pragma unroll
    for (int rr = 0; rr < 2; rr++) {
      As[ak + rr * 16 + 0][arow] = pa[rr].x;
      As[ak + rr * 16 + 1][arow] = pa[rr].y;
      As[ak + rr * 16 + 2][arow] = pa[rr].z;
      As[ak + rr * 16 + 3][arow] = pa[rr].w;
      *reinterpret_cast<float4*>(&Bs[brow][bn + rr * 64]) = pb[rr];
    }
    __syncthreads();
    // prefetch next tile into regs (overlaps with compute below)
    if (kb + 32 < CDIM) {
#pragma unroll
      for (int rr = 0; rr < 2; rr++) {
        pa[rr] = *reinterpret_cast<const float4*>(
            &X[(size_t)(m0 + arow) * CDIM + kb + 32 + ak + rr * 16]);
        pb[rr] = *reinterpret_cast<const float4*>(
            &Wqk[(size_t)(kb + 32 + brow) * CDIM + n0 + bn + rr * 64]);
      }
    }
#pragma unroll
    for (int k = 0; k < 32; k++) {
      float4 a0 = *reinterpret_cast<const float4*>(&As[k][r * 8]);
      float4 a1 = *reinterpret_cast<const float4*>(&As[k][r * 8 + 4]);
      float4 b  = *reinterpret_cast<const float4*>(&Bs[k][c * 4]);
      float am[8] = {a0.x, a0.y, a0.z, a0.w, a1.x, a1.y, a1.z, a1.w};
      f32x2 b01 = {b.x, b.y};
      f32x2 b23 = {b.z, b.w};
#pragma unroll
      for (int i = 0; i < 8; i++) {
        f32x2 av = {am[i], am[i]};
        acc2[i][0] += av * b01;   // fmuladd per component, k-ascending chain
        acc2[i][1] += av * b23;
      }
    }
    __syncthreads();
  }
  // epilogue: rows m0+r*8+ii, cols n0 + c*4 (head = (n0>>6)+(c>>4))
  const int head = (n0 >> 6) + (c >> 4);
#pragma unroll
  for (int ii = 0; ii < 8; ii++) {
    int m = m0 + r * 8 + ii;
    int b = m >> 12, t = m & 4095;
    size_t base = ((size_t)(b * 8 + head) * LSEQ + t) * DHD + (c & 15) * 4;
    float4 ov = {acc2[ii][0][0], acc2[ii][0][1], acc2[ii][1][0], acc2[ii][1][1]};
    *reinterpret_cast<float4*>(&qk[base]) = ov;
    uint32_t h0 = cvtpk_bf16(ov.x, ov.y);
    uint32_t h1 = cvtpk_bf16(ov.z, ov.w);
    float r0 = ov.x - __uint_as_float(h0 << 16);
    float r1 = ov.y - __uint_as_float(h0 & 0xffff0000u);
    float r2 = ov.z - __uint_as_float(h1 << 16);
    float r3 = ov.w - __uint_as_float(h1 & 0xffff0000u);
    *reinterpret_cast<uint2*>(&qkhi[base]) = {h0, h1};
    *reinterpret_cast<uint2*>(&qklo[base]) = {cvtpk_bf16(r0, r1), cvtpk_bf16(r2, r3)};
    float ss = ov.x * ov.x + ov.y * ov.y + ov.z * ov.z + ov.w * ov.w;
    ss += __shfl_xor(ss, 1, 64);
    ss += __shfl_xor(ss, 2, 64);
    ss += __shfl_xor(ss, 4, 64);
    ss += __shfl_xor(ss, 8, 64);
    if ((c & 15) == 0)
      invn_g[(size_t)(b * 8 + head) * LSEQ + t] = 1.0f / fmaxf(sqrtf(ss), 1e-12f);
  }
}

// ---------------------------------------------------------------------------
// K1b: v projection via bf16-split MFMA (3-term).  X split now INLINED
// (X consumed once -> in-register cvtpk split at staging; same bit-values
// as the old prep path).  grid (128, 4), block 512.
// ---------------------------------------------------------------------------
__global__ __launch_bounds__(512) void gemm_v_mfma_kernel(
    const float* __restrict__ Xf,
    const uint16_t* __restrict__ Wv0, const uint16_t* __restrict__ Wv1,
    uint16_t* __restrict__ vhi)
{
  __shared__ __align__(16) uint16_t Xs[2 * 128 * 40];
  __shared__ __align__(16) uint16_t Ws[2 * 128 * 40];
  const int tid = threadIdx.x;
  const int m0 = blockIdx.x * 128;
  const int n0 = blockIdx.y * 128;
  const int lane = tid & 63, w = tid >> 6;
  const int l16 = lane & 15, lg = lane >> 4;

  f32x4 acc[8];
#pragma unroll
  for (int nt = 0; nt < 8; nt++) acc[nt] = {0.f, 0.f, 0.f, 0.f};

  const int srow = tid >> 3;          // 0..63
  const int sch = (tid & 7) * 4;      // u16 offset within 32-k row

  for (int kb = 0; kb < CDIM; kb += 32) {
    // stage X: load f32, split in-register (cvtpk — identical bits to prep)
#pragma unroll
    for (int i = 0; i < 2; i++) {
      int row = i * 64 + srow;
      float4 v = *reinterpret_cast<const float4*>(
          &Xf[(size_t)(m0 + row) * CDIM + kb + sch]);
      uint32_t h01 = cvtpk_bf16(v.x, v.y);
      uint32_t h23 = cvtpk_bf16(v.z, v.w);
      float r0 = v.x - __uint_as_float(h01 << 16);
      float r1 = v.y - __uint_as_float(h01 & 0xffff0000u);
      float r2 = v.z - __uint_as_float(h23 << 16);
      float r3 = v.w - __uint_as_float(h23 & 0xffff0000u);
      uint2 hw = {h01, h23};
      uint2 lw = {cvtpk_bf16(r0, r1), cvtpk_bf16(r2, r3)};
      *reinterpret_cast<uint2*>(Xs + row * 40 + sch) = hw;
      *reinterpret_cast<uint2*>(Xs + 5120 + row * 40 + sch) = lw;
    }
    // stage W planes (bf16 copies)
#pragma unroll
    for (int i = 0; i < 4; i++) {
      int p = i >> 1;
      int row = (i & 1) * 64 + srow;
      const uint16_t* wg = (p == 0) ? Wv0 : Wv1;
      *reinterpret_cast<uint2*>(Ws + p * 5120 + row * 40 + sch) =
          *reinterpret_cast<const uint2*>(wg + (size_t)(n0 + row) * 512 + kb + sch);
    }
    __syncthreads();

    const int abase = (w * 16 + l16) * 40 + lg * 8;
    short8 a0 = *reinterpret_cast<const short8*>(Xs + abase);
    short8 a1 = *reinterpret_cast<const short8*>(Xs + 5120 + abase);
#pragma unroll
    for (int nt = 0; nt < 8; nt++) {
      int bbase = (nt * 16 + l16) * 40 + lg * 8;
      short8 b0 = *reinterpret_cast<const short8*>(Ws + bbase);
      short8 b1 = *reinterpret_cast<const short8*>(Ws + 5120 + bbase);
      acc[nt] = __builtin_amdgcn_mfma_f32_16x16x32_bf16(a0, b0, acc[nt], 0, 0, 0);
      acc[nt] = __builtin_amdgcn_mfma_f32_16x16x32_bf16(a1, b0, acc[nt], 0, 0, 0);
      acc[nt] = __builtin_amdgcn_mfma_f32_16x16x32_bf16(a0, b1, acc[nt], 0, 0, 0);
    }
    __syncthreads();
  }

#pragma unroll
  for (int rr = 0; rr < 4; rr++) {
    int mg = m0 + w * 16 + lg * 4 + rr;
    int b = mg >> 12, t = mg & 4095;
#pragma unroll
    for (int nt = 0; nt < 8; nt++) {
      int head = (n0 >> 6) + (nt >> 2);
      size_t base = ((size_t)(b * 8 + head) * LSEQ + t) * DHD + (nt & 3) * 16 + l16;
      vhi[base] = (uint16_t)cvtpk_bf16(acc[nt][rr], acc[nt][rr]);
    }
  }
}

// ---------------------------------------------------------------------------
// K2: LSH hashing.  UNCHANGED (bucket determinism; reads frozen f32 qk).
// ---------------------------------------------------------------------------
__global__ __launch_bounds__(256) void hash_kernel(
    const float* __restrict__ qk, const float* __restrict__ rot,
    int* __restrict__ buckets)
{
  __shared__ float rotT[128][68];   // [h*32+i][f]
  const int tid = threadIdx.x;
  for (int idx = tid; idx < 64 * 128; idx += 256) {
    int f = idx >> 7, hi = idx & 127;
    rotT[hi][f] = rot[idx];
  }
  __syncthreads();
  const int bh = blockIdx.y;
  const int t = blockIdx.x * 256 + tid;
  float4 row4[16];
  const float* src = &qk[((size_t)bh * LSEQ + t) * DHD];
#pragma unroll
  for (int i = 0; i < 16; i++) row4[i] = reinterpret_cast<const float4*>(src)[i];

  int* bout = &buckets[(size_t)bh * NHASH * LSEQ];
  for (int h = 0; h < NHASH; h++) {
    float rc[32];
    float best = -3.0e38f;
    int bidx = 0;
#pragma unroll 4
    for (int i = 0; i < 32; i++) {
      const float* rr = &rotT[h * 32 + i][0];
      float a = 0.f;
#pragma unroll
      for (int f4 = 0; f4 < 16; f4++) {
        float4 rv = reinterpret_cast<const float4*>(rr)[f4];
        a += row4[f4].x * rv.x + row4[f4].y * rv.y + row4[f4].z * rv.z + row4[f4].w * rv.w;
      }
      rc[i] = a;
      if (a > best) { best = a; bidx = i; }
    }
#pragma unroll
    for (int i = 0; i < 32; i++) {
      float nv = -rc[i];
      if (nv > best) { best = nv; bidx = 32 + i; }
    }
    bout[h * LSEQ + t] = bidx;
  }
}

// ---------------------------------------------------------------------------
// K3: stable counting sort per (bh, h).  UNCHANGED (r11-passing ballot
// multi-split — exact integer logic).
// ---------------------------------------------------------------------------
__global__ __launch_bounds__(256) void sort_kernel(
    const int* __restrict__ buckets, int* __restrict__ st)
{
  __shared__ int hist[64][64];
  const int h = blockIdx.x, bh = blockIdx.y;
  const int tid = threadIdx.x;
  const int* bk = &buckets[((size_t)bh * NHASH + h) * LSEQ];

  for (int i = tid; i < 64 * 64; i += 256) (&hist[0][0])[i] = 0;
  __syncthreads();
  for (int t = tid; t < LSEQ; t += 256) {
    int b = bk[t];
    atomicAdd(&hist[t >> 6][b], 1);
  }
  __syncthreads();
  if (tid < 64) {
    int tot = 0;
    for (int s = 0; s < 64; s++) tot += hist[s][tid];
    int vsc = tot;
    for (int off = 1; off < 64; off <<= 1) {
      int nv = __shfl_up(vsc, off, 64);
      if (tid >= off) vsc += nv;
    }
    int run = h * LSEQ + (vsc - tot);
    for (int s = 0; s < 64; s++) {
      int tmp = hist[s][tid];
      hist[s][tid] = run;
      run += tmp;
    }
  }
  __syncthreads();
  const int wave = tid >> 6, lane = tid & 63;
  const uint64_t below = (lane == 63) ? 0x7fffffffffffffffull
                                      : ((1ull << lane) - 1ull);
  for (int si = 0; si < 16; si++) {
    int seg = wave * 16 + si;
    int pos = seg * 64 + lane;
    int b = bk[pos];
    // multi-split: mask of lanes whose 6-bit bucket equals mine
    uint64_t same = ~0ull;
#pragma unroll
    for (int j = 0; j < 6; j++) {
      uint64_t bal = __ballot((b >> j) & 1);
      same &= ((b >> j) & 1) ? bal : ~bal;
    }
    int rank = __popcll(same & below);
    int dest = hist[seg][b] + rank;
    st[(size_t)bh * (NHASH * LSEQ) + dest] = pos;
  }
}

// ---------------------------------------------------------------------------
// K4: chunked attention.  UNCHANGED (r11-passing: XCD swizzle + cvt_pk +
// s_setprio around MFMA clusters).
// ---------------------------------------------------------------------------
__global__ __launch_bounds__(256) void attn_kernel(
    const uint16_t* __restrict__ qkhi, const uint16_t* __restrict__ qklo,
    const uint16_t* __restrict__ vhi, const float* __restrict__ invn_g,
    const int* __restrict__ st, uint16_t* __restrict__ o,
    float* __restrict__ lse_out)
{
  __shared__ __align__(16) uint8_t smem[53248];
  uint16_t* Khi  = (uint16_t*)smem;                  // [128][68] = 17408 B
  uint16_t* Klo  = Khi + 128 * 68;                   // +17408 B
  uint16_t* Vthi = (uint16_t*)(smem + 34816);        // [64][128] = 16384 B
  float*    invn = (float*)(smem + 52224);           // 128 f
  int*      kpos = (int*)(smem + 52736);             // 128 i
  uint32_t* P32  = (uint32_t*)smem;                  // [64][132] u32, alias K

  // XCD-aware swizzle: lin -> (xcd, idx); each XCD gets 4 bh x 256 chunks
  const int lin = blockIdx.y * 256 + blockIdx.x;
  const int xcd = lin & 7, sidx = lin >> 3;
  const int bh = (xcd << 2) | (sidx >> 8);
  const int cchunk = sidx & 255;

  const int tid = threadIdx.x;
  const int prev = (cchunk + NCHUNK - 1) & (NCHUNK - 1);
  const int* stb = &st[(size_t)bh * (NHASH * LSEQ)];
  const int h = cchunk >> 6;

  if (tid < 128) {
    int kp = (tid < 64) ? stb[prev * 64 + tid] : stb[cchunk * 64 + (tid - 64)];
    kpos[tid] = kp;
    invn[tid] = invn_g[(size_t)bh * LSEQ + kp];
  }
  __syncthreads();

  // ---- stage K planes (pure copies) ----
  {
    const int d4 = tid & 15, rbase = tid >> 4;
    const uint16_t* qhb = qkhi + (size_t)bh * LSEQ * DHD;
    const uint16_t* qlb = qklo + (size_t)bh * LSEQ * DHD;
#pragma unroll
    for (int it = 0; it < 8; it++) {
      int row = rbase + it * 16;
      size_t src = (size_t)kpos[row] * DHD + d4 * 4;
      *reinterpret_cast<uint2*>(Khi + row * 68 + d4 * 4) =
          *reinterpret_cast<const uint2*>(qhb + src);
      *reinterpret_cast<uint2*>(Klo + row * 68 + d4 * 4) =
          *reinterpret_cast<const uint2*>(qlb + src);
    }
  }
  // ---- stage V transposed (u16 4x4 transpose), swizzled ----
  {
    const int d4 = tid & 15, jg0 = tid >> 4;
    const uint16_t* vb = vhi + (size_t)bh * LSEQ * DHD;
#pragma unroll
    for (int half = 0; half < 2; half++) {
      int jg = jg0 + half * 16;   // 0..31, j = 4*jg..4*jg+3
      uint2 vr[4];
#pragma unroll
      for (int s = 0; s < 4; s++)
        vr[s] = *reinterpret_cast<const uint2*>(vb + (size_t)kpos[jg * 4 + s] * DHD + d4 * 4);
#pragma unroll
      for (int i = 0; i < 4; i++) {
        int d = d4 * 4 + i;
        uint32_t e0 = (((i & 2) ? vr[0].y : vr[0].x) >> ((i & 1) * 16)) & 0xffffu;
        uint32_t e1 = (((i & 2) ? vr[1].y : vr[1].x) >> ((i & 1) * 16)) & 0xffffu;
        uint32_t e2 = (((i & 2) ? vr[2].y : vr[2].x) >> ((i & 1) * 16)) & 0xffffu;
        uint32_t e3 = (((i & 2) ? vr[3].y : vr[3].x) >> ((i & 1) * 16)) & 0xffffu;
        uint2 outw = {e0 | (e1 << 16), e2 | (e3 << 16)};
        int cpr = (jg >> 1) ^ (d & 15);
        *reinterpret_cast<uint2*>(Vthi + d * 128 + cpr * 8 + (jg & 1) * 4) = outw;
      }
    }
  }
  __syncthreads();

  const int lane = tid & 63, w = tid >> 6;
  const int l16 = lane & 15, lg = lane >> 4;

  // ---- QK^T (bf16x3), wave w -> q-rows 16w..16w+15 ----
  f32x4 acc[8];
#pragma unroll
  for (int nt = 0; nt < 8; nt++) acc[nt] = {0.f, 0.f, 0.f, 0.f};

  __builtin_amdgcn_s_setprio(1);
#pragma unroll
  for (int ks = 0; ks < 2; ks++) {
    int aoff = (64 + w * 16 + l16) * 68 + ks * 32 + lg * 8;
    short8 a_hi = ldsK(Khi + aoff);
    short8 a_lo = ldsK(Klo + aoff);
#pragma unroll
    for (int nt = 0; nt < 8; nt++) {
      int boff = (nt * 16 + l16) * 68 + ks * 32 + lg * 8;
      short8 b_hi = ldsK(Khi + boff);
      short8 b_lo = ldsK(Klo + boff);
      acc[nt] = __builtin_amdgcn_mfma_f32_16x16x32_bf16(a_hi, b_hi, acc[nt], 0, 0, 0);
      acc[nt] = __builtin_amdgcn_mfma_f32_16x16x32_bf16(a_lo, b_hi, acc[nt], 0, 0, 0);
      acc[nt] = __builtin_amdgcn_mfma_f32_16x16x32_bf16(a_hi, b_lo, acc[nt], 0, 0, 0);
    }
  }
  __builtin_amdgcn_s_setprio(0);

  // ---- register softmax on the D-layout ----
  float invc[8]; int kpc[8];
#pragma unroll
  for (int nt = 0; nt < 8; nt++) {
    invc[nt] = invn[nt * 16 + l16] * 0.125f;
    kpc[nt] = kpos[nt * 16 + l16];
  }
  float pll[4];
#pragma unroll
  for (int r = 0; r < 4; r++) {
    int q = w * 16 + lg * 4 + r;
    int qp = kpos[64 + q];
    float mm = -3.0e38f;
#pragma unroll
    for (int nt = 0; nt < 8; nt++) {
      float s = acc[nt][r] * invc[nt];
      if (qp == kpc[nt]) s = -5e4f;
      acc[nt][r] = s;
      mm = fmaxf(mm, s);
    }
    mm = fmaxf(mm, __shfl_xor(mm, 1, 64));
    mm = fmaxf(mm, __shfl_xor(mm, 2, 64));
    mm = fmaxf(mm, __shfl_xor(mm, 4, 64));
    mm = fmaxf(mm, __shfl_xor(mm, 8, 64));
    float ll = 0.f;
#pragma unroll
    for (int nt = 0; nt < 8; nt++) {
      float p = __expf(acc[nt][r] - mm);
      acc[nt][r] = p;
      ll += p;
    }
    ll += __shfl_xor(ll, 1, 64);
    ll += __shfl_xor(ll, 2, 64);
    ll += __shfl_xor(ll, 4, 64);
    ll += __shfl_xor(ll, 8, 64);
    if (l16 == 0)
      lse_out[(size_t)bh * (NHASH * LSEQ) + h * LSEQ + qp] = mm + __logf(ll);
    pll[r] = 1.0f / ll;
  }
  __syncthreads();   // all K-plane reads done; safe to alias P32

  // ---- write P (packed hi|lo u32, via cvt_pk) ----
#pragma unroll
  for (int r = 0; r < 4; r++) {
    int q = w * 16 + lg * 4 + r;
#pragma unroll
    for (int nt = 0; nt < 8; nt++) {
      float p = acc[nt][r];
      uint32_t t1 = cvtpk_bf16(p, p);
      float res = p - __uint_as_float(t1 << 16);
      P32[q * 132 + nt * 16 + l16] = cvtpk_bf16(p, res);   // low=phi, high=plo
    }
  }
  // no barrier: wave reads back only its own 16 P rows

  // ---- PV: O = P.Vhi (2-term) ----
  f32x4 oacc[4];
#pragma unroll
  for (int nt = 0; nt < 4; nt++) oacc[nt] = {0.f, 0.f, 0.f, 0.f};

  __builtin_amdgcn_s_setprio(1);
#pragma unroll
  for (int ks = 0; ks < 4; ks++) {
    const uint32_t* pr = P32 + (w * 16 + l16) * 132 + ks * 32 + lg * 8;
    uint4 ua = *reinterpret_cast<const uint4*>(pr);
    uint4 ub = *reinterpret_cast<const uint4*>(pr + 4);
    uint32_t u[8] = {ua.x, ua.y, ua.z, ua.w, ub.x, ub.y, ub.z, ub.w};
    union { uint32_t w4[4]; short8 s8; } ph, pl;
#pragma unroll
    for (int k2 = 0; k2 < 4; k2++) {
      ph.w4[k2] = (u[2 * k2] & 0xffffu) | (u[2 * k2 + 1] << 16);
      pl.w4[k2] = (u[2 * k2] >> 16) | (u[2 * k2 + 1] & 0xffff0000u);
    }
    const int cc = ks * 4 + lg;
#pragma unroll
    for (int nt = 0; nt < 4; nt++) {
      int voff = (nt * 16 + l16) * 128 + ((cc ^ l16) & 15) * 8;
      short8 v_hi = *reinterpret_cast<const short8*>(Vthi + voff);
      oacc[nt] = __builtin_amdgcn_mfma_f32_16x16x32_bf16(ph.s8, v_hi, oacc[nt], 0, 0, 0);
      oacc[nt] = __builtin_amdgcn_mfma_f32_16x16x32_bf16(pl.s8, v_hi, oacc[nt], 0, 0, 0);
    }
  }
  __builtin_amdgcn_s_setprio(0);

  // ---- normalize + write O (bf16, unsorted) ----
  {
    uint16_t* ob = o + ((size_t)bh * (NHASH * LSEQ) + (size_t)h * LSEQ) * DHD;
#pragma unroll
    for (int r = 0; r < 4; r++) {
      int q = w * 16 + lg * 4 + r;
      int qp = kpos[64 + q];
      float s = pll[r];
#pragma unroll
      for (int nt = 0; nt < 4; nt++) {
        float v = oacc[nt][r] * s;
        ob[(size_t)qp * DHD + nt * 16 + l16] = (uint16_t)cvtpk_bf16(v, v);
      }
    }
  }
}

// ---------------------------------------------------------------------------
// K5: combine hash rounds -> comb bf16 hi/lo planes (cvt_pk).  UNCHANGED.
// ---------------------------------------------------------------------------
__global__ __launch_bounds__(256) void combine_kernel(
    const uint16_t* __restrict__ o, const float* __restrict__ lse,
    uint16_t* __restrict__ comb_hi, uint16_t* __restrict__ comb_lo)
{
  int gid = blockIdx.x * 4 + (threadIdx.x >> 6);
  int lane = threadIdx.x & 63;
  int bh = gid >> 12;
  int pos = gid & 4095;
  const float* lb = &lse[(size_t)bh * (NHASH * LSEQ) + pos];
  float l0 = lb[0], l1 = lb[LSEQ], l2 = lb[2 * LSEQ], l3 = lb[3 * LSEQ];
  float m = fmaxf(fmaxf(l0, l1), fmaxf(l2, l3));
  float w0 = __expf(l0 - m), w1 = __expf(l1 - m), w2 = __expf(l2 - m), w3 = __expf(l3 - m);
  float inv = 1.0f / (w0 + w1 + w2 + w3);
  const uint16_t* ob = &o[((size_t)bh * (NHASH * LSEQ) + pos) * DHD];
  float val = (w0 * bf2f(ob[lane]) + w1 * bf2f(ob[(size_t)LSEQ * DHD + lane]) +
               w2 * bf2f(ob[(size_t)2 * LSEQ * DHD + lane]) +
               w3 * bf2f(ob[(size_t)3 * LSEQ * DHD + lane])) * inv;
  int b = bh >> 3, head = bh & 7;
  size_t idx = ((size_t)(b * LSEQ + pos)) * CDIM + head * DHD + lane;
  uint32_t hw = cvtpk_bf16(val, val);
  float res = val - __uint_as_float(hw << 16);
  comb_hi[idx] = (uint16_t)hw;
  comb_lo[idx] = (uint16_t)cvtpk_bf16(res, res);
}

// ---------------------------------------------------------------------------
// K6: output GEMM, bf16x3 MFMA — v2: 8-wave/512-thread gemm_v-style
// structure (24 MFMA per wave per k-step, LDS 40960 -> better occupancy).
// grid (128, 4), block 512.
// ---------------------------------------------------------------------------
__global__ __launch_bounds__(512) void gemm_out_kernel(
    const uint16_t* __restrict__ Ahi_g, const uint16_t* __restrict__ Alo_g,
    const uint16_t* __restrict__ Bhi_g, const uint16_t* __restrict__ Blo_g,
    const float* __restrict__ bias, float* __restrict__ out)
{
  __shared__ __align__(16) uint16_t Ah[128 * 40];
  __shared__ __align__(16) uint16_t Al[128 * 40];
  __shared__ __align__(16) uint16_t Bh[128 * 40];
  __shared__ __align__(16) uint16_t Bl[128 * 40];
  const int tid = threadIdx.x;
  const int m0 = blockIdx.x * 128, n0 = blockIdx.y * 128;
  const int lane = tid & 63, w = tid >> 6;
  const int l16 = lane & 15, lg = lane >> 4;

  f32x4 acc[8];
#pragma unroll
  for (int nt = 0; nt < 8; nt++) acc[nt] = {0.f, 0.f, 0.f, 0.f};

  const int srow = tid >> 2;        // 0..127
  const int sch  = (tid & 3) * 8;   // u16 offset: 0,8,16,24 (16B chunks)

  for (int kb = 0; kb < CDIM; kb += 32) {
    *reinterpret_cast<uint4*>(Ah + srow * 40 + sch) =
        *reinterpret_cast<const uint4*>(Ahi_g + (size_t)(m0 + srow) * CDIM + kb + sch);
    *reinterpret_cast<uint4*>(Al + srow * 40 + sch) =
        *reinterpret_cast<const uint4*>(Alo_g + (size_t)(m0 + srow) * CDIM + kb + sch);
    *reinterpret_cast<uint4*>(Bh + srow * 40 + sch) =
        *reinterpret_cast<const uint4*>(Bhi_g + (size_t)(n0 + srow) * CDIM + kb + sch);
    *reinterpret_cast<uint4*>(Bl + srow * 40 + sch) =
        *reinterpret_cast<const uint4*>(Blo_g + (size_t)(n0 + srow) * CDIM + kb + sch);
    __syncthreads();

    const int abase = (w * 16 + l16) * 40 + lg * 8;
    short8 ah = *reinterpret_cast<const short8*>(Ah + abase);
    short8 al = *reinterpret_cast<const short8*>(Al + abase);
#pragma unroll
    for (int nt = 0; nt < 8; nt++) {
      int bbase = (nt * 16 + l16) * 40 + lg * 8;
      short8 bh_ = *reinterpret_cast<const short8*>(Bh + bbase);
      short8 bl_ = *reinterpret_cast<const short8*>(Bl + bbase);
      acc[nt] = __builtin_amdgcn_mfma_f32_16x16x32_bf16(ah, bh_, acc[nt], 0, 0, 0);
      acc[nt] = __builtin_amdgcn_mfma_f32_16x16x32_bf16(al, bh_, acc[nt], 0, 0, 0);
      acc[nt] = __builtin_amdgcn_mfma_f32_16x16x32_bf16(ah, bl_, acc[nt], 0, 0, 0);
    }
    __syncthreads();
  }
  // epilogue: wave w rows 16w.., D[row=lg*4+rr][col=nt*16+l16] + bias
#pragma unroll
  for (int nt = 0; nt < 8; nt++) {
    int n = n0 + nt * 16 + l16;
    float bv = bias[n];
#pragma unroll
    for (int rr = 0; rr < 4; rr++) {
      int mg = m0 + w * 16 + lg * 4 + rr;
      out[(size_t)mg * CDIM + n] = acc[nt][rr] + bv;
    }
  }
}

// ---------------------------------------------------------------------------
extern "C" void kernel_launch(void* const* d_in, const int* in_sizes, int n_in,
                              void* d_out, int out_size, void* d_ws, size_t ws_size,
                              hipStream_t stream) {
  (void)in_sizes; (void)n_in; (void)out_size; (void)ws_size;
  const float* X    = (const float*)d_in[0];   // queries (4,4096,512)
  const float* Wqk  = (const float*)d_in[6];
  const float* Wv   = (const float*)d_in[7];
  const float* Wo   = (const float*)d_in[8];
  const float* bo   = (const float*)d_in[9];
  const float* rot  = (const float*)d_in[10];  // (64, 4, 32)

  // workspace layout (bytes), peak ~160 MB
  uint8_t* W = (uint8_t*)d_ws;
  float*    qk      = (float*)(W + 0);              // 33,554,432 B
  uint16_t* obuf    = (uint16_t*)(W + 33554432);    // 67,108,864 B
  uint16_t* qkhi    = (uint16_t*)(W + 100663296);   // 16,777,216 B
  uint16_t* qklo    = (uint16_t*)(W + 117440512);   // 16,777,216 B
  uint16_t* vhi     = (uint16_t*)(W + 134217728);   // 16,777,216 B
  int*      buckets = (int*)(W + 150994944);        //  2,097,152 B
  int*      st      = (int*)(W + 153092096);        //  2,097,152 B
  float*    lse     = (float*)(W + 155189248);      //  2,097,152 B
  float*    invn_g  = (float*)(W + 157286400);      //    524,288 B
  uint16_t* woT_hi  = (uint16_t*)(W + 157810688);   //    524,288 B
  uint16_t* woT_lo  = (uint16_t*)(W + 158334976);   //    524,288 B
  uint16_t* wvT0    = (uint16_t*)(W + 158859264);   //    524,288 B
  uint16_t* wvT1    = (uint16_t*)(W + 159383552);   // end 159,907,840
  uint16_t* comb_hi = (uint16_t*)(W + 0);           // alias qk (dead post-hash)
  uint16_t* comb_lo = (uint16_t*)(W + 16777216);

  hipLaunchKernelGGL(prep_kernel, dim3(1280), dim3(256), 0, stream,
                     Wv, Wo, wvT0, wvT1, woT_hi, woT_lo);
  hipLaunchKernelGGL(gemm_qk_kernel, dim3(128, 4), dim3(512), 0, stream,
                     X, Wqk, qk, qkhi, qklo, invn_g);
  hipLaunchKernelGGL(gemm_v_mfma_kernel, dim3(128, 4), dim3(512), 0, stream,
                     X, wvT0, wvT1, vhi);
  hipLaunchKernelGGL(hash_kernel, dim3(16, 32), dim3(256), 0, stream,
                     qk, rot, buckets);
  hipLaunchKernelGGL(sort_kernel, dim3(4, 32), dim3(256), 0, stream,
                     buckets, st);
  hipLaunchKernelGGL(attn_kernel, dim3(256, 32), dim3(256), 0, stream,
                     qkhi, qklo, vhi, invn_g, st, obuf, lse);
  hipLaunchKernelGGL(combine_kernel, dim3(32768), dim3(256), 0, stream,
                     obuf, lse, comb_hi, comb_lo);
  hipLaunchKernelGGL(gemm_out_kernel, dim3(128, 4), dim3(512), 0, stream,
                     comb_hi, comb_lo, woT_hi, woT_lo, bo, (float*)d_out);
}